// Round 1
// baseline (4904.836 us; speedup 1.0000x reference)
//
#include <hip/hip_runtime.h>
#include <math.h>

// InterRankAttention: graph attention message passing.
// Pipeline:
//  1) Node-level GEMMs: Hs=src@Ws+bs [N,512], Ht=tgt@Wt+bt [M,512], Hm=src@Wm+bm [N,128]
//  2) CSR build (histogram + scan + scatter) grouping edges by target
//  3) One wave per target: online-softmax attention over its edges, fused with
//     weighted aggregation of Hm rows -> agg [M,128]
//  4) out = agg@Wo + bo

__device__ __forceinline__ float gelu_f(float x) {
    return 0.5f * x * (1.0f + erff(x * 0.70710678118654752f));
}

// ---------------- CSR build ----------------
__global__ void hist_kernel(const int* __restrict__ tgt, int* __restrict__ counts, int E) {
    int e = blockIdx.x * blockDim.x + threadIdx.x;
    if (e < E) atomicAdd(&counts[tgt[e]], 1);
}

__global__ __launch_bounds__(1024)
void scan_kernel(const int* __restrict__ counts, int* __restrict__ offsets, int M) {
    __shared__ int sdata[1024];
    int tid = threadIdx.x;
    int chunk = (M + 1023) / 1024;
    int lo = tid * chunk;
    int hi = lo + chunk; if (hi > M) hi = M; if (lo > M) lo = M;
    int sum = 0;
    for (int i = lo; i < hi; ++i) sum += counts[i];
    sdata[tid] = sum;
    __syncthreads();
    int v = sum;
    for (int d = 1; d < 1024; d <<= 1) {
        int other = (tid >= d) ? sdata[tid - d] : 0;
        __syncthreads();
        v += other;
        sdata[tid] = v;
        __syncthreads();
    }
    int run = v - sum;  // exclusive prefix
    for (int i = lo; i < hi; ++i) { offsets[i] = run; run += counts[i]; }
    if (tid == 1023) offsets[M] = v;  // total = E
}

__global__ void scatter_kernel(const int* __restrict__ tgt, const int* __restrict__ offsets,
                               int* __restrict__ cursor, int* __restrict__ perm, int E) {
    int e = blockIdx.x * blockDim.x + threadIdx.x;
    if (e < E) {
        int t = tgt[e];
        int r = atomicAdd(&cursor[t], 1);
        perm[offsets[t] + r] = e;
    }
}

// ---------------- f32 GEMM: C[M x N] = A[M x 128] @ B[128 x N] + bias ----------------
// BM=64, BN=64, full K=128 staged in LDS. 256 threads, each computes 4x4.
#define MM(A0,A1,A2,A3,BV) \
    acc00 += A0 * BV.x; acc01 += A0 * BV.y; acc02 += A0 * BV.z; acc03 += A0 * BV.w; \
    acc10 += A1 * BV.x; acc11 += A1 * BV.y; acc12 += A1 * BV.z; acc13 += A1 * BV.w; \
    acc20 += A2 * BV.x; acc21 += A2 * BV.y; acc22 += A2 * BV.z; acc23 += A2 * BV.w; \
    acc30 += A3 * BV.x; acc31 += A3 * BV.y; acc32 += A3 * BV.z; acc33 += A3 * BV.w;

__global__ __launch_bounds__(256)
void gemm128_kernel(const float* __restrict__ A, const float* __restrict__ B,
                    const float* __restrict__ bias, float* __restrict__ C,
                    int Mrows, int Ncols) {
    __shared__ float As[64][132];   // [m][k], padded: +4 keeps 16B align, breaks conflicts
    __shared__ float Bs[128][64];   // [k][n]
    int tid = threadIdx.x;
    int bx = blockIdx.x, by = blockIdx.y;
    int row0 = by * 64, col0 = bx * 64;

    // Load A tile 64x128 (2048 float4, 8 per thread)
#pragma unroll
    for (int l = 0; l < 8; ++l) {
        int f4 = l * 256 + tid;
        int m  = f4 >> 5;            // /32 float4 per row
        int k4 = (f4 & 31) << 2;
        int row = row0 + m;
        float4 v = make_float4(0.f, 0.f, 0.f, 0.f);
        if (row < Mrows) v = *(const float4*)(A + (size_t)row * 128 + k4);
        *(float4*)(&As[m][k4]) = v;
    }
    // Load B tile 128x64 (2048 float4, 8 per thread); N is a multiple of 64, no guard
#pragma unroll
    for (int l = 0; l < 8; ++l) {
        int f4 = l * 256 + tid;
        int k  = f4 >> 4;            // /16 float4 per row
        int c4 = (f4 & 15) << 2;
        float4 v = *(const float4*)(B + (size_t)k * Ncols + col0 + c4);
        *(float4*)(&Bs[k][c4]) = v;
    }
    __syncthreads();

    int ty = tid >> 4, tx = tid & 15;  // 16x16 threads, 4x4 outputs each
    float acc00=0,acc01=0,acc02=0,acc03=0, acc10=0,acc11=0,acc12=0,acc13=0;
    float acc20=0,acc21=0,acc22=0,acc23=0, acc30=0,acc31=0,acc32=0,acc33=0;

#pragma unroll
    for (int k = 0; k < 128; k += 4) {
        float4 a0 = *(const float4*)(&As[ty * 4 + 0][k]);
        float4 a1 = *(const float4*)(&As[ty * 4 + 1][k]);
        float4 a2 = *(const float4*)(&As[ty * 4 + 2][k]);
        float4 a3 = *(const float4*)(&As[ty * 4 + 3][k]);
        float4 b0 = *(const float4*)(&Bs[k + 0][tx * 4]);
        float4 b1 = *(const float4*)(&Bs[k + 1][tx * 4]);
        float4 b2 = *(const float4*)(&Bs[k + 2][tx * 4]);
        float4 b3 = *(const float4*)(&Bs[k + 3][tx * 4]);
        MM(a0.x, a1.x, a2.x, a3.x, b0)
        MM(a0.y, a1.y, a2.y, a3.y, b1)
        MM(a0.z, a1.z, a2.z, a3.z, b2)
        MM(a0.w, a1.w, a2.w, a3.w, b3)
    }

    float4 bv = *(const float4*)(bias + col0 + tx * 4);
    int rbase = row0 + ty * 4;
    int cb = col0 + tx * 4;
    if (rbase + 0 < Mrows) *(float4*)(C + (size_t)(rbase + 0) * Ncols + cb) =
        make_float4(acc00 + bv.x, acc01 + bv.y, acc02 + bv.z, acc03 + bv.w);
    if (rbase + 1 < Mrows) *(float4*)(C + (size_t)(rbase + 1) * Ncols + cb) =
        make_float4(acc10 + bv.x, acc11 + bv.y, acc12 + bv.z, acc13 + bv.w);
    if (rbase + 2 < Mrows) *(float4*)(C + (size_t)(rbase + 2) * Ncols + cb) =
        make_float4(acc20 + bv.x, acc21 + bv.y, acc22 + bv.z, acc23 + bv.w);
    if (rbase + 3 < Mrows) *(float4*)(C + (size_t)(rbase + 3) * Ncols + cb) =
        make_float4(acc30 + bv.x, acc31 + bv.y, acc32 + bv.z, acc33 + bv.w);
}

// ---------------- fused per-target online-softmax attention + aggregation ----------------
// One wave (64 lanes) per target. Lane l owns hidden dims [8l,8l+8) and output
// dims {2l,2l+1}; both belong to head l/16, so the 16-lane butterfly reduction
// delivers exactly the head this lane accumulates for.
__global__ __launch_bounds__(256)
void attn_kernel(const float* __restrict__ Hs, const float* __restrict__ Ht,
                 const float* __restrict__ Hm, const float* __restrict__ attn_w,
                 const int* __restrict__ edge_sources, const int* __restrict__ offsets,
                 const int* __restrict__ perm, float* __restrict__ agg, int M) {
    int wave = threadIdx.x >> 6;
    int lane = threadIdx.x & 63;
    int t = blockIdx.x * 4 + wave;
    if (t >= M) return;

    int j0 = lane << 3;
    const float4* htp = (const float4*)(Ht + (size_t)t * 512 + j0);
    float4 ht0 = htp[0], ht1 = htp[1];
    const float4* awp = (const float4*)(attn_w + j0);
    float4 aw0 = awp[0], aw1 = awp[1];

    int off = offsets[t];
    int deg = offsets[t + 1] - off;

    float m = -INFINITY, den = 0.f, acc0 = 0.f, acc1 = 0.f;
    for (int i = 0; i < deg; ++i) {
        int e = perm[off + i];
        int s = edge_sources[e];
        const float4* hsp = (const float4*)(Hs + (size_t)s * 512 + j0);
        float4 h0 = hsp[0], h1 = hsp[1];
        float q;
        q  = gelu_f(h0.x + ht0.x) * aw0.x;
        q += gelu_f(h0.y + ht0.y) * aw0.y;
        q += gelu_f(h0.z + ht0.z) * aw0.z;
        q += gelu_f(h0.w + ht0.w) * aw0.w;
        q += gelu_f(h1.x + ht1.x) * aw1.x;
        q += gelu_f(h1.y + ht1.y) * aw1.y;
        q += gelu_f(h1.z + ht1.z) * aw1.z;
        q += gelu_f(h1.w + ht1.w) * aw1.w;
        // reduce over the 16 lanes of this head group
        q += __shfl_xor(q, 1);
        q += __shfl_xor(q, 2);
        q += __shfl_xor(q, 4);
        q += __shfl_xor(q, 8);

        float2 hm = *(const float2*)(Hm + (size_t)s * 128 + (lane << 1));
        float nm = fmaxf(m, q);
        float sc = __expf(m - nm);   // first iter: exp(-inf)=0
        float p  = __expf(q - nm);
        den  = den  * sc + p;
        acc0 = acc0 * sc + p * hm.x;
        acc1 = acc1 * sc + p * hm.y;
        m = nm;
    }
    float r = (deg > 0) ? (1.0f / den) : 0.0f;
    float2 o; o.x = acc0 * r; o.y = acc1 * r;
    *(float2*)(agg + (size_t)t * 128 + (lane << 1)) = o;
}

extern "C" void kernel_launch(void* const* d_in, const int* in_sizes, int n_in,
                              void* d_out, int out_size, void* d_ws, size_t ws_size,
                              hipStream_t stream) {
    const float* src_f  = (const float*)d_in[0];
    const float* tgt_f  = (const float*)d_in[1];
    const int*   e_tgt  = (const int*)d_in[2];
    const int*   e_src  = (const int*)d_in[3];
    const float* Ws     = (const float*)d_in[4];
    const float* bs     = (const float*)d_in[5];
    const float* Wt     = (const float*)d_in[6];
    const float* bt     = (const float*)d_in[7];
    const float* attn_w = (const float*)d_in[8];
    const float* Wm     = (const float*)d_in[9];
    const float* bm     = (const float*)d_in[10];
    const float* Wo     = (const float*)d_in[11];
    const float* bo     = (const float*)d_in[12];

    int N = in_sizes[0] / 128;
    int M = in_sizes[1] / 128;
    int E = in_sizes[2];

    char* ws = (char*)d_ws;
    size_t woff = 0;
    auto alloc = [&](size_t bytes) -> void* {
        void* p = ws + woff;
        woff += ((bytes + 255) / 256) * 256;
        return p;
    };
    float* Hs      = (float*)alloc((size_t)N * 512 * 4);
    float* Ht      = (float*)alloc((size_t)M * 512 * 4);
    float* Hm      = (float*)alloc((size_t)N * 128 * 4);
    float* agg     = (float*)alloc((size_t)M * 128 * 4);
    int*   counts  = (int*)alloc((size_t)M * 4);
    int*   cursor  = (int*)alloc((size_t)M * 4);
    int*   offsets = (int*)alloc((size_t)(M + 1) * 4);
    int*   perm    = (int*)alloc((size_t)E * 4);

    hipMemsetAsync(counts, 0, (size_t)M * 4, stream);
    hipMemsetAsync(cursor, 0, (size_t)M * 4, stream);

    const int tb = 256;
    hist_kernel<<<(E + tb - 1) / tb, tb, 0, stream>>>(e_tgt, counts, E);
    scan_kernel<<<1, 1024, 0, stream>>>(counts, offsets, M);
    scatter_kernel<<<(E + tb - 1) / tb, tb, 0, stream>>>(e_tgt, offsets, cursor, perm, E);

    dim3 gs(512 / 64, (N + 63) / 64);
    gemm128_kernel<<<gs, 256, 0, stream>>>(src_f, Ws, bs, Hs, N, 512);
    dim3 gt(512 / 64, (M + 63) / 64);
    gemm128_kernel<<<gt, 256, 0, stream>>>(tgt_f, Wt, bt, Ht, M, 512);
    dim3 gm(128 / 64, (N + 63) / 64);
    gemm128_kernel<<<gm, 256, 0, stream>>>(src_f, Wm, bm, Hm, N, 128);

    attn_kernel<<<(M + 3) / 4, 256, 0, stream>>>(Hs, Ht, Hm, attn_w, e_src, offsets, perm, agg, M);

    dim3 go(128 / 64, (M + 63) / 64);
    gemm128_kernel<<<go, 256, 0, stream>>>(agg, Wo, bo, (float*)d_out, M, 128);
}

// Round 2
// 666.275 us; speedup vs baseline: 7.3616x; 7.3616x over previous
//
#include <hip/hip_runtime.h>
#include <math.h>

// InterRankAttention: graph attention message passing.
// Pipeline:
//  1) Fused node GEMM: Hsm = src@[Ws|Wm] + [bs|bm]  [N,640]  (cols 0..511 = Hs, 512..639 = Hm)
//     Ht = tgt@Wt + bt [M,512]
//  2) CSR build (histogram + scan + scatter) grouping edges by target
//  3) One wave per target: online-softmax attention fused with weighted aggregation -> agg [M,128]
//  4) out = agg@Wo + bo

__device__ __forceinline__ float gelu_f(float x) {
    return 0.5f * x * (1.0f + erff(x * 0.70710678118654752f));
}

// ---------------- CSR build ----------------
__global__ void hist_kernel(const int* __restrict__ tgt, int* __restrict__ counts, int E) {
    int e = blockIdx.x * blockDim.x + threadIdx.x;
    if (e < E) atomicAdd(&counts[tgt[e]], 1);
}

__global__ __launch_bounds__(1024)
void scan_kernel(const int* __restrict__ counts, int* __restrict__ offsets, int M) {
    __shared__ int sdata[1024];
    int tid = threadIdx.x;
    int chunk = (M + 1023) / 1024;
    int lo = tid * chunk;
    int hi = lo + chunk; if (hi > M) hi = M; if (lo > M) lo = M;
    int sum = 0;
    for (int i = lo; i < hi; ++i) sum += counts[i];
    sdata[tid] = sum;
    __syncthreads();
    int v = sum;
    for (int d = 1; d < 1024; d <<= 1) {
        int other = (tid >= d) ? sdata[tid - d] : 0;
        __syncthreads();
        v += other;
        sdata[tid] = v;
        __syncthreads();
    }
    int run = v - sum;  // exclusive prefix
    for (int i = lo; i < hi; ++i) { offsets[i] = run; run += counts[i]; }
    if (tid == 1023) offsets[M] = v;  // total = E
}

__global__ void scatter_kernel(const int* __restrict__ tgt, const int* __restrict__ offsets,
                               int* __restrict__ cursor, int* __restrict__ perm, int E) {
    int e = blockIdx.x * blockDim.x + threadIdx.x;
    if (e < E) {
        int t = tgt[e];
        int r = atomicAdd(&cursor[t], 1);
        perm[offsets[t] + r] = e;
    }
}

// ---------------- f32 GEMM: C[Mrows x Ntot] = A[Mrows x 128] @ [B0 | B1] + [bias0 | bias1] ----
// BM=64, BN=64, BK=64 (two phases over K=128). 256 threads, 4x4 per thread.
// LDS 33 KB -> 4 blocks/CU; __launch_bounds__(256,4) caps VGPR at 128.
// Column split: blocks with col0 < n0 use B0 [128 x n0] / bias0, else B1 [128 x (Ntot-n0)] / bias1.
#define MM(A0,A1,A2,A3,BV) \
    acc00 += A0 * BV.x; acc01 += A0 * BV.y; acc02 += A0 * BV.z; acc03 += A0 * BV.w; \
    acc10 += A1 * BV.x; acc11 += A1 * BV.y; acc12 += A1 * BV.z; acc13 += A1 * BV.w; \
    acc20 += A2 * BV.x; acc21 += A2 * BV.y; acc22 += A2 * BV.z; acc23 += A2 * BV.w; \
    acc30 += A3 * BV.x; acc31 += A3 * BV.y; acc32 += A3 * BV.z; acc33 += A3 * BV.w;

__global__ __launch_bounds__(256, 4)
void gemm128_kernel(const float* __restrict__ A,
                    const float* __restrict__ B0, int n0,
                    const float* __restrict__ B1,
                    const float* __restrict__ bias0, const float* __restrict__ bias1,
                    float* __restrict__ C, int Mrows, int Ntot) {
    __shared__ float As[64][68];   // [m][k], +4 pad: rows land on banks +4 apart
    __shared__ float Bs[64][64];   // [k][n]
    int tid = threadIdx.x;
    int bx = blockIdx.x, by = blockIdx.y;
    int row0 = by * 64, col0 = bx * 64;

    const float* Bsrc; const float* biasSrc; int ldb; int colL;
    if (col0 < n0) { Bsrc = B0; biasSrc = bias0; ldb = n0;        colL = col0; }
    else           { Bsrc = B1; biasSrc = bias1; ldb = Ntot - n0; colL = col0 - n0; }

    int ty = tid >> 4, tx = tid & 15;  // 16x16 threads, 4x4 outputs each
    float acc00=0,acc01=0,acc02=0,acc03=0, acc10=0,acc11=0,acc12=0,acc13=0;
    float acc20=0,acc21=0,acc22=0,acc23=0, acc30=0,acc31=0,acc32=0,acc33=0;

    for (int kb = 0; kb < 128; kb += 64) {
        // Load A tile 64x64 (1024 float4, 4 per thread)
#pragma unroll
        for (int l = 0; l < 4; ++l) {
            int f4 = l * 256 + tid;
            int m  = f4 >> 4;            // 16 float4 per row
            int k4 = (f4 & 15) << 2;
            int row = row0 + m;
            float4 v = make_float4(0.f, 0.f, 0.f, 0.f);
            if (row < Mrows) v = *(const float4*)(A + (size_t)row * 128 + kb + k4);
            *(float4*)(&As[m][k4]) = v;
        }
        // Load B tile 64x64 (N always a multiple of 64, no guard)
#pragma unroll
        for (int l = 0; l < 4; ++l) {
            int f4 = l * 256 + tid;
            int k  = f4 >> 4;
            int c4 = (f4 & 15) << 2;
            float4 v = *(const float4*)(Bsrc + (size_t)(kb + k) * ldb + colL + c4);
            *(float4*)(&Bs[k][c4]) = v;
        }
        __syncthreads();

#pragma unroll 4
        for (int k = 0; k < 64; k += 4) {
            float4 a0 = *(const float4*)(&As[ty * 4 + 0][k]);
            float4 a1 = *(const float4*)(&As[ty * 4 + 1][k]);
            float4 a2 = *(const float4*)(&As[ty * 4 + 2][k]);
            float4 a3 = *(const float4*)(&As[ty * 4 + 3][k]);
            float4 b0 = *(const float4*)(&Bs[k + 0][tx * 4]);
            float4 b1 = *(const float4*)(&Bs[k + 1][tx * 4]);
            float4 b2 = *(const float4*)(&Bs[k + 2][tx * 4]);
            float4 b3 = *(const float4*)(&Bs[k + 3][tx * 4]);
            MM(a0.x, a1.x, a2.x, a3.x, b0)
            MM(a0.y, a1.y, a2.y, a3.y, b1)
            MM(a0.z, a1.z, a2.z, a3.z, b2)
            MM(a0.w, a1.w, a2.w, a3.w, b3)
        }
        __syncthreads();
    }

    float4 bv = *(const float4*)(biasSrc + colL + tx * 4);
    int rbase = row0 + ty * 4;
    int cb = col0 + tx * 4;
    if (rbase + 0 < Mrows) *(float4*)(C + (size_t)(rbase + 0) * Ntot + cb) =
        make_float4(acc00 + bv.x, acc01 + bv.y, acc02 + bv.z, acc03 + bv.w);
    if (rbase + 1 < Mrows) *(float4*)(C + (size_t)(rbase + 1) * Ntot + cb) =
        make_float4(acc10 + bv.x, acc11 + bv.y, acc12 + bv.z, acc13 + bv.w);
    if (rbase + 2 < Mrows) *(float4*)(C + (size_t)(rbase + 2) * Ntot + cb) =
        make_float4(acc20 + bv.x, acc21 + bv.y, acc22 + bv.z, acc23 + bv.w);
    if (rbase + 3 < Mrows) *(float4*)(C + (size_t)(rbase + 3) * Ntot + cb) =
        make_float4(acc30 + bv.x, acc31 + bv.y, acc32 + bv.z, acc33 + bv.w);
}

// ---------------- fused per-target online-softmax attention + aggregation ----------------
// One wave (64 lanes) per target. Lane l owns hidden dims [8l,8l+8) and output
// dims {2l,2l+1}; both belong to head l/16, so the 16-lane butterfly reduction
// delivers exactly the head this lane accumulates for.
// Hsm layout: row s = [Hs (512 floats) | Hm (128 floats)], stride 640.
__global__ __launch_bounds__(256)
void attn_kernel(const float* __restrict__ Hsm, const float* __restrict__ Ht,
                 const float* __restrict__ attn_w,
                 const int* __restrict__ edge_sources, const int* __restrict__ offsets,
                 const int* __restrict__ perm, float* __restrict__ agg, int M) {
    int wave = threadIdx.x >> 6;
    int lane = threadIdx.x & 63;
    int t = blockIdx.x * 4 + wave;
    if (t >= M) return;

    int j0 = lane << 3;
    const float4* htp = (const float4*)(Ht + (size_t)t * 512 + j0);
    float4 ht0 = htp[0], ht1 = htp[1];
    const float4* awp = (const float4*)(attn_w + j0);
    float4 aw0 = awp[0], aw1 = awp[1];

    int off = offsets[t];
    int deg = offsets[t + 1] - off;

    float m = -INFINITY, den = 0.f, acc0 = 0.f, acc1 = 0.f;
    for (int i = 0; i < deg; ++i) {
        int e = perm[off + i];
        int s = edge_sources[e];
        const float* hrow = Hsm + (size_t)s * 640;
        const float4* hsp = (const float4*)(hrow + j0);
        float4 h0 = hsp[0], h1 = hsp[1];
        float q;
        q  = gelu_f(h0.x + ht0.x) * aw0.x;
        q += gelu_f(h0.y + ht0.y) * aw0.y;
        q += gelu_f(h0.z + ht0.z) * aw0.z;
        q += gelu_f(h0.w + ht0.w) * aw0.w;
        q += gelu_f(h1.x + ht1.x) * aw1.x;
        q += gelu_f(h1.y + ht1.y) * aw1.y;
        q += gelu_f(h1.z + ht1.z) * aw1.z;
        q += gelu_f(h1.w + ht1.w) * aw1.w;
        // reduce over the 16 lanes of this head group
        q += __shfl_xor(q, 1);
        q += __shfl_xor(q, 2);
        q += __shfl_xor(q, 4);
        q += __shfl_xor(q, 8);

        float2 hm = *(const float2*)(hrow + 512 + (lane << 1));
        float nm = fmaxf(m, q);
        float sc = __expf(m - nm);   // first iter: exp(-inf)=0
        float p  = __expf(q - nm);
        den  = den  * sc + p;
        acc0 = acc0 * sc + p * hm.x;
        acc1 = acc1 * sc + p * hm.y;
        m = nm;
    }
    float r = (deg > 0) ? (1.0f / den) : 0.0f;
    float2 o; o.x = acc0 * r; o.y = acc1 * r;
    *(float2*)(agg + (size_t)t * 128 + (lane << 1)) = o;
}

extern "C" void kernel_launch(void* const* d_in, const int* in_sizes, int n_in,
                              void* d_out, int out_size, void* d_ws, size_t ws_size,
                              hipStream_t stream) {
    const float* src_f  = (const float*)d_in[0];
    const float* tgt_f  = (const float*)d_in[1];
    const int*   e_tgt  = (const int*)d_in[2];
    const int*   e_src  = (const int*)d_in[3];
    const float* Ws     = (const float*)d_in[4];
    const float* bs     = (const float*)d_in[5];
    const float* Wt     = (const float*)d_in[6];
    const float* bt     = (const float*)d_in[7];
    const float* attn_w = (const float*)d_in[8];
    const float* Wm     = (const float*)d_in[9];
    const float* bm     = (const float*)d_in[10];
    const float* Wo     = (const float*)d_in[11];
    const float* bo     = (const float*)d_in[12];

    int N = in_sizes[0] / 128;
    int M = in_sizes[1] / 128;
    int E = in_sizes[2];

    char* ws = (char*)d_ws;
    size_t woff = 0;
    auto alloc = [&](size_t bytes) -> void* {
        void* p = ws + woff;
        woff += ((bytes + 255) / 256) * 256;
        return p;
    };
    float* Hsm     = (float*)alloc((size_t)N * 640 * 4);   // [Hs | Hm]
    float* Ht      = (float*)alloc((size_t)M * 512 * 4);
    float* agg     = (float*)alloc((size_t)M * 128 * 4);
    int*   counts  = (int*)alloc((size_t)M * 4);
    int*   cursor  = (int*)alloc((size_t)M * 4);
    int*   offsets = (int*)alloc((size_t)(M + 1) * 4);
    int*   perm    = (int*)alloc((size_t)E * 4);

    hipMemsetAsync(counts, 0, (size_t)M * 4, stream);
    hipMemsetAsync(cursor, 0, (size_t)M * 4, stream);

    const int tb = 256;
    hist_kernel<<<(E + tb - 1) / tb, tb, 0, stream>>>(e_tgt, counts, E);
    scan_kernel<<<1, 1024, 0, stream>>>(counts, offsets, M);
    scatter_kernel<<<(E + tb - 1) / tb, tb, 0, stream>>>(e_tgt, offsets, cursor, perm, E);

    // Hsm = src @ [Ws | Wm] + [bs | bm]   (640 cols: 512 from Ws, 128 from Wm)
    dim3 gs(640 / 64, (N + 63) / 64);
    gemm128_kernel<<<gs, 256, 0, stream>>>(src_f, Ws, 512, Wm, bs, bm, Hsm, N, 640);
    // Ht = tgt @ Wt + bt
    dim3 gt(512 / 64, (M + 63) / 64);
    gemm128_kernel<<<gt, 256, 0, stream>>>(tgt_f, Wt, 512, nullptr, bt, nullptr, Ht, M, 512);

    attn_kernel<<<(M + 3) / 4, 256, 0, stream>>>(Hsm, Ht, attn_w, e_src, offsets, perm, agg, M);

    // out = agg @ Wo + bo
    dim3 go(128 / 64, (M + 63) / 64);
    gemm128_kernel<<<go, 256, 0, stream>>>(agg, Wo, 128, nullptr, bo, nullptr, (float*)d_out, M, 128);
}

// Round 4
// 530.289 us; speedup vs baseline: 9.2494x; 1.2564x over previous
//
#include <hip/hip_runtime.h>
#include <math.h>

// InterRankAttention — R4: bf16 MFMA GEMMs (in-register f32->bf16 A-staging,
// no cast buffers: workspace kept under the known-good 258 MB) + tanh-gelu attention.
// Pipeline:
//  0) Build transposed bf16 weight buffer WT[1280][128]
//     (rows 0..639 = [Ws|Wm]^T, 640..1151 = Wt^T, 1152..1279 = Wo^T) + bias_cat[640]=[bs|bm]
//  1) MFMA GEMMs: Hsm = src@[Ws|Wm]+[bs|bm] [N,640] f32;  Ht = tgt@Wt+bt [M,512] f32
//  2) CSR build (histogram + scan + scatter) grouping edges by target
//  3) One wave per target: online-softmax attention (tanh-gelu) fused with weighted
//     aggregation -> agg [M,128] bf16
//  4) out = agg@Wo + bo (MFMA GEMM, f32 out)

typedef __bf16 bf16x8 __attribute__((ext_vector_type(8)));
typedef float  f32x4  __attribute__((ext_vector_type(4)));

__device__ __forceinline__ unsigned short f2bf(float x) {
    unsigned u = __float_as_uint(x);
    u += 0x7FFFu + ((u >> 16) & 1u);   // round-to-nearest-even
    return (unsigned short)(u >> 16);
}

// tanh-form GELU: 0.5x(1+tanh(0.79788456(x+0.044715x^3))) = x - x/(exp(2u)+1)
__device__ __forceinline__ float gelu_f(float x) {
    float x2 = x * x;
    float u  = x * fmaf(0.0713548163f, x2, 1.5957691216f);
    float e  = __expf(u);
    float r  = __builtin_amdgcn_rcpf(e + 1.0f);
    return fmaf(-x, r, x);
}

// ---------------- weight prep ----------------
// One block per output row n (1280 rows), 128 threads = k.
__global__ __launch_bounds__(128)
void prep_weights_kernel(const float* __restrict__ Ws, const float* __restrict__ Wm,
                         const float* __restrict__ Wt, const float* __restrict__ Wo,
                         const float* __restrict__ bs, const float* __restrict__ bm,
                         unsigned short* __restrict__ WT, float* __restrict__ bias_cat) {
    int n = blockIdx.x, k = threadIdx.x;
    float w;
    if      (n < 512)  w = Ws[(size_t)k * 512 + n];
    else if (n < 640)  w = Wm[(size_t)k * 128 + (n - 512)];
    else if (n < 1152) w = Wt[(size_t)k * 512 + (n - 640)];
    else               w = Wo[(size_t)k * 128 + (n - 1152)];
    WT[(size_t)n * 128 + k] = f2bf(w);
    if (k == 0 && n < 640) bias_cat[n] = (n < 512) ? bs[n] : bm[n - 512];
}

// ---------------- CSR build ----------------
__global__ void hist_kernel(const int* __restrict__ tgt, int* __restrict__ counts, int E) {
    int e = blockIdx.x * blockDim.x + threadIdx.x;
    if (e < E) atomicAdd(&counts[tgt[e]], 1);
}

__global__ __launch_bounds__(1024)
void scan_kernel(const int* __restrict__ counts, int* __restrict__ offsets, int M) {
    __shared__ int sdata[1024];
    int tid = threadIdx.x;
    int chunk = (M + 1023) / 1024;
    int lo = tid * chunk;
    int hi = lo + chunk; if (hi > M) hi = M; if (lo > M) lo = M;
    int sum = 0;
    for (int i = lo; i < hi; ++i) sum += counts[i];
    sdata[tid] = sum;
    __syncthreads();
    int v = sum;
    for (int d = 1; d < 1024; d <<= 1) {
        int other = (tid >= d) ? sdata[tid - d] : 0;
        __syncthreads();
        v += other;
        sdata[tid] = v;
        __syncthreads();
    }
    int run = v - sum;  // exclusive prefix
    for (int i = lo; i < hi; ++i) { offsets[i] = run; run += counts[i]; }
    if (tid == 1023) offsets[M] = v;
}

__global__ void scatter_kernel(const int* __restrict__ tgt, const int* __restrict__ offsets,
                               int* __restrict__ cursor, int* __restrict__ perm, int E) {
    int e = blockIdx.x * blockDim.x + threadIdx.x;
    if (e < E) {
        int t = tgt[e];
        int r = atomicAdd(&cursor[t], 1);
        perm[offsets[t] + r] = e;
    }
}

// ---------------- bf16 MFMA GEMM ----------------
// C[Mrows x Ntot] f32 = A[Mrows x 128] @ BT^T + bias; BT stored [Ntot][128] bf16.
// A is f32 (converted to bf16 while staging into LDS) or bf16, per template flag.
// 64x64 tile, K=128, 256 threads = 4 waves, each wave 32x32 via 2x2 mfma_f32_16x16x32_bf16.
template <bool A_IS_F32>
__global__ __launch_bounds__(256)
void gemm_bf16_kernel(const void* __restrict__ Araw,
                      const unsigned short* __restrict__ BT,
                      const float* __restrict__ bias,
                      float* __restrict__ C, int Mrows, int Ntot) {
    __shared__ unsigned short As[64 * 136];  // [m][k], row stride 136 shorts: 16B-aligned rows
    __shared__ unsigned short Bs[64 * 136];  // [n][k]
    int tid = threadIdx.x;
    int row0 = blockIdx.y * 64, col0 = blockIdx.x * 64;

    // Stage A tile: 64 rows x 128 elems = 1024 chunks of 8, 4 per thread
#pragma unroll
    for (int l = 0; l < 4; ++l) {
        int idx = l * 256 + tid;
        int r = idx >> 4, c8 = idx & 15;
        int row = row0 + r;
        if (A_IS_F32) {
            const float* Af = (const float*)Araw;
            float4 v0 = make_float4(0.f, 0.f, 0.f, 0.f), v1 = v0;
            if (row < Mrows) {
                v0 = *(const float4*)(Af + (size_t)row * 128 + c8 * 8);
                v1 = *(const float4*)(Af + (size_t)row * 128 + c8 * 8 + 4);
            }
            ushort4 o0, o1;
            o0.x = f2bf(v0.x); o0.y = f2bf(v0.y); o0.z = f2bf(v0.z); o0.w = f2bf(v0.w);
            o1.x = f2bf(v1.x); o1.y = f2bf(v1.y); o1.z = f2bf(v1.z); o1.w = f2bf(v1.w);
            *(ushort4*)(&As[r * 136 + c8 * 8])     = o0;
            *(ushort4*)(&As[r * 136 + c8 * 8 + 4]) = o1;
        } else {
            const unsigned short* Ab = (const unsigned short*)Araw;
            uint4 v = make_uint4(0, 0, 0, 0);
            if (row < Mrows) v = *(const uint4*)(Ab + (size_t)row * 128 + c8 * 8);
            *(uint4*)(&As[r * 136 + c8 * 8]) = v;
        }
    }
    // Stage B tile: 64 n-rows x 128 bf16 (Ntot multiple of 64, no guard)
#pragma unroll
    for (int l = 0; l < 4; ++l) {
        int idx = l * 256 + tid;
        int r = idx >> 4, c8 = idx & 15;
        uint4 v = *(const uint4*)(BT + (size_t)(col0 + r) * 128 + c8 * 8);
        *(uint4*)(&Bs[r * 136 + c8 * 8]) = v;
    }
    __syncthreads();

    int wid = tid >> 6, lane = tid & 63;
    int wm = (wid >> 1) * 32, wn = (wid & 1) * 32;
    int g = lane >> 4, r16 = lane & 15;

    f32x4 acc00 = {0.f, 0.f, 0.f, 0.f}, acc01 = acc00, acc10 = acc00, acc11 = acc00;

#pragma unroll
    for (int kk = 0; kk < 4; ++kk) {
        int k0 = kk * 32 + g * 8;
        bf16x8 a0 = *(const bf16x8*)(&As[(wm + r16) * 136 + k0]);
        bf16x8 a1 = *(const bf16x8*)(&As[(wm + 16 + r16) * 136 + k0]);
        bf16x8 b0 = *(const bf16x8*)(&Bs[(wn + r16) * 136 + k0]);
        bf16x8 b1 = *(const bf16x8*)(&Bs[(wn + 16 + r16) * 136 + k0]);
        acc00 = __builtin_amdgcn_mfma_f32_16x16x32_bf16(a0, b0, acc00, 0, 0, 0);
        acc01 = __builtin_amdgcn_mfma_f32_16x16x32_bf16(a0, b1, acc01, 0, 0, 0);
        acc10 = __builtin_amdgcn_mfma_f32_16x16x32_bf16(a1, b0, acc10, 0, 0, 0);
        acc11 = __builtin_amdgcn_mfma_f32_16x16x32_bf16(a1, b1, acc11, 0, 0, 0);
    }

    // C/D layout: col = lane&15, row = (lane>>4)*4 + reg
    float bv0 = bias[col0 + wn + r16];
    float bv1 = bias[col0 + wn + 16 + r16];
#pragma unroll
    for (int i = 0; i < 4; ++i) {
        int rA = row0 + wm + g * 4 + i;
        int rB = rA + 16;
        if (rA < Mrows) {
            C[(size_t)rA * Ntot + col0 + wn + r16]      = acc00[i] + bv0;
            C[(size_t)rA * Ntot + col0 + wn + 16 + r16] = acc01[i] + bv1;
        }
        if (rB < Mrows) {
            C[(size_t)rB * Ntot + col0 + wn + r16]      = acc10[i] + bv0;
            C[(size_t)rB * Ntot + col0 + wn + 16 + r16] = acc11[i] + bv1;
        }
    }
}

// ---------------- fused per-target online-softmax attention + aggregation ----------------
// One wave per target. Lane l owns hidden dims [8l,8l+8) and output dims {2l,2l+1};
// both map to head l/16, so the 16-lane butterfly reduce lands the right head's logit.
// Hsm row s = [Hs (512) | Hm (128)] f32, stride 640. agg written as bf16 [M,128].
__global__ __launch_bounds__(256)
void attn_kernel(const float* __restrict__ Hsm, const float* __restrict__ Ht,
                 const float* __restrict__ attn_w,
                 const int* __restrict__ edge_sources, const int* __restrict__ offsets,
                 const int* __restrict__ perm, unsigned short* __restrict__ agg, int M) {
    int wave = threadIdx.x >> 6;
    int lane = threadIdx.x & 63;
    int t = blockIdx.x * 4 + wave;
    if (t >= M) return;

    int j0 = lane << 3;
    const float4* htp = (const float4*)(Ht + (size_t)t * 512 + j0);
    float4 ht0 = htp[0], ht1 = htp[1];
    const float4* awp = (const float4*)(attn_w + j0);
    float4 aw0 = awp[0], aw1 = awp[1];

    int off = offsets[t];
    int deg = offsets[t + 1] - off;

    float m = -INFINITY, den = 0.f, acc0 = 0.f, acc1 = 0.f;
    for (int i = 0; i < deg; ++i) {
        int e = perm[off + i];
        int s = edge_sources[e];
        const float* hrow = Hsm + (size_t)s * 640;
        const float4* hsp = (const float4*)(hrow + j0);
        float4 h0 = hsp[0], h1 = hsp[1];
        float q;
        q  = gelu_f(h0.x + ht0.x) * aw0.x;
        q += gelu_f(h0.y + ht0.y) * aw0.y;
        q += gelu_f(h0.z + ht0.z) * aw0.z;
        q += gelu_f(h0.w + ht0.w) * aw0.w;
        q += gelu_f(h1.x + ht1.x) * aw1.x;
        q += gelu_f(h1.y + ht1.y) * aw1.y;
        q += gelu_f(h1.z + ht1.z) * aw1.z;
        q += gelu_f(h1.w + ht1.w) * aw1.w;
        q += __shfl_xor(q, 1);
        q += __shfl_xor(q, 2);
        q += __shfl_xor(q, 4);
        q += __shfl_xor(q, 8);

        float2 hm = *(const float2*)(hrow + 512 + (lane << 1));
        float nm = fmaxf(m, q);
        float sc = __expf(m - nm);   // first iter: exp(-inf)=0
        float p  = __expf(q - nm);
        den  = den  * sc + p;
        acc0 = acc0 * sc + p * hm.x;
        acc1 = acc1 * sc + p * hm.y;
        m = nm;
    }
    float r = (deg > 0) ? __builtin_amdgcn_rcpf(den) : 0.0f;
    ushort2 o;
    o.x = f2bf(acc0 * r);
    o.y = f2bf(acc1 * r);
    *(ushort2*)(agg + (size_t)t * 128 + (lane << 1)) = o;
}

extern "C" void kernel_launch(void* const* d_in, const int* in_sizes, int n_in,
                              void* d_out, int out_size, void* d_ws, size_t ws_size,
                              hipStream_t stream) {
    const float* src_f  = (const float*)d_in[0];
    const float* tgt_f  = (const float*)d_in[1];
    const int*   e_tgt  = (const int*)d_in[2];
    const int*   e_src  = (const int*)d_in[3];
    const float* Ws     = (const float*)d_in[4];
    const float* bs     = (const float*)d_in[5];
    const float* Wt     = (const float*)d_in[6];
    const float* bt     = (const float*)d_in[7];
    const float* attn_w = (const float*)d_in[8];
    const float* Wm     = (const float*)d_in[9];
    const float* bm     = (const float*)d_in[10];
    const float* Wo     = (const float*)d_in[11];
    const float* bo     = (const float*)d_in[12];

    int N = in_sizes[0] / 128;
    int M = in_sizes[1] / 128;
    int E = in_sizes[2];

    char* ws = (char*)d_ws;
    size_t woff = 0;
    auto alloc = [&](size_t bytes) -> void* {
        void* p = ws + woff;
        woff += ((bytes + 255) / 256) * 256;
        return p;
    };
    // Total ~245.7 MB (must stay under the R2-proven ~258 MB footprint)
    float*          Hsm      = (float*)alloc((size_t)N * 640 * 4);
    float*          Ht       = (float*)alloc((size_t)M * 512 * 4);
    unsigned short* agg_bf   = (unsigned short*)alloc((size_t)M * 128 * 2);
    unsigned short* WT       = (unsigned short*)alloc((size_t)1280 * 128 * 2);
    float*          bias_cat = (float*)alloc(640 * 4);
    int*            counts   = (int*)alloc((size_t)M * 4);
    int*            cursor   = (int*)alloc((size_t)M * 4);
    int*            offsets  = (int*)alloc((size_t)(M + 1) * 4);
    int*            perm     = (int*)alloc((size_t)E * 4);

    hipMemsetAsync(counts, 0, (size_t)M * 4, stream);
    hipMemsetAsync(cursor, 0, (size_t)M * 4, stream);

    const int tb = 256;
    // CSR build
    hist_kernel<<<(E + tb - 1) / tb, tb, 0, stream>>>(e_tgt, counts, E);
    scan_kernel<<<1, 1024, 0, stream>>>(counts, offsets, M);
    scatter_kernel<<<(E + tb - 1) / tb, tb, 0, stream>>>(e_tgt, offsets, cursor, perm, E);

    // Weight prep
    prep_weights_kernel<<<1280, 128, 0, stream>>>(Ws, Wm, Wt, Wo, bs, bm, WT, bias_cat);

    // Hsm = src @ [Ws|Wm] + [bs|bm]
    dim3 gs(640 / 64, (N + 63) / 64);
    gemm_bf16_kernel<true><<<gs, 256, 0, stream>>>(src_f, WT, bias_cat, Hsm, N, 640);
    // Ht = tgt @ Wt + bt
    dim3 gt(512 / 64, (M + 63) / 64);
    gemm_bf16_kernel<true><<<gt, 256, 0, stream>>>(tgt_f, WT + (size_t)640 * 128, bt, Ht, M, 512);

    attn_kernel<<<(M + 3) / 4, 256, 0, stream>>>(Hsm, Ht, attn_w, e_src, offsets, perm, agg_bf, M);

    // out = agg @ Wo + bo
    dim3 go(128 / 64, (M + 63) / 64);
    gemm_bf16_kernel<false><<<go, 256, 0, stream>>>(agg_bf, WT + (size_t)1152 * 128, bo, (float*)d_out, M, 128);
}

// Round 5
// 441.148 us; speedup vs baseline: 11.1183x; 1.2021x over previous
//
#include <hip/hip_runtime.h>
#include <math.h>

// InterRankAttention — R5: split-bf16 (hi+lo) MFMA hidden GEMMs for ~f32 accuracy,
// bf16 storage of Hs/Ht/Hm (halves attn gather working set -> L3-resident),
// 2-edge-unrolled online-softmax attention, pre-gathered source ids in CSR.

typedef __bf16 bf16x8 __attribute__((ext_vector_type(8)));
typedef float  f32x4  __attribute__((ext_vector_type(4)));

__device__ __forceinline__ unsigned short f2bf(float x) {
    unsigned u = __float_as_uint(x);
    u += 0x7FFFu + ((u >> 16) & 1u);   // round-to-nearest-even
    return (unsigned short)(u >> 16);
}
__device__ __forceinline__ float bf2f(unsigned short b) {
    return __uint_as_float(((unsigned)b) << 16);
}
// unpack a dword holding 2 bf16 (little-endian: low short = first element)
__device__ __forceinline__ void unpack2(unsigned u, float& a, float& b) {
    a = __uint_as_float(u << 16);
    b = __uint_as_float(u & 0xFFFF0000u);
}

// tanh-form GELU: x - x/(exp(1.5957691216x + 0.0713548163x^3)+1)
__device__ __forceinline__ float gelu_f(float x) {
    float x2 = x * x;
    float u  = x * fmaf(0.0713548163f, x2, 1.5957691216f);
    float e  = __expf(u);
    float r  = __builtin_amdgcn_rcpf(e + 1.0f);
    return fmaf(-x, r, x);
}

// ---------------- weight prep: WT_hi/WT_lo [1280][128] bf16 + bias_cat[640] ----------------
// rows 0..511 = Ws^T, 512..639 = Wm^T, 640..1151 = Wt^T, 1152..1279 = Wo^T
__global__ __launch_bounds__(128)
void prep_weights_kernel(const float* __restrict__ Ws, const float* __restrict__ Wm,
                         const float* __restrict__ Wt, const float* __restrict__ Wo,
                         const float* __restrict__ bs, const float* __restrict__ bm,
                         unsigned short* __restrict__ WThi, unsigned short* __restrict__ WTlo,
                         float* __restrict__ bias_cat) {
    int n = blockIdx.x, k = threadIdx.x;
    float w;
    if      (n < 512)  w = Ws[(size_t)k * 512 + n];
    else if (n < 640)  w = Wm[(size_t)k * 128 + (n - 512)];
    else if (n < 1152) w = Wt[(size_t)k * 512 + (n - 640)];
    else               w = Wo[(size_t)k * 128 + (n - 1152)];
    unsigned short hi = f2bf(w);
    WThi[(size_t)n * 128 + k] = hi;
    WTlo[(size_t)n * 128 + k] = f2bf(w - bf2f(hi));
    if (k == 0 && n < 640) bias_cat[n] = (n < 512) ? bs[n] : bm[n - 512];
}

// ---------------- CSR build ----------------
__global__ void hist_kernel(const int* __restrict__ tgt, int* __restrict__ counts, int E) {
    int e = blockIdx.x * blockDim.x + threadIdx.x;
    if (e < E) atomicAdd(&counts[tgt[e]], 1);
}

__global__ __launch_bounds__(1024)
void scan_kernel(const int* __restrict__ counts, int* __restrict__ offsets, int M) {
    __shared__ int sdata[1024];
    int tid = threadIdx.x;
    int chunk = (M + 1023) / 1024;
    int lo = tid * chunk;
    int hi = lo + chunk; if (hi > M) hi = M; if (lo > M) lo = M;
    int sum = 0;
    for (int i = lo; i < hi; ++i) sum += counts[i];
    sdata[tid] = sum;
    __syncthreads();
    int v = sum;
    for (int d = 1; d < 1024; d <<= 1) {
        int other = (tid >= d) ? sdata[tid - d] : 0;
        __syncthreads();
        v += other;
        sdata[tid] = v;
        __syncthreads();
    }
    int run = v - sum;  // exclusive prefix
    for (int i = lo; i < hi; ++i) { offsets[i] = run; run += counts[i]; }
    if (tid == 1023) offsets[M] = v;
}

// Writes pre-gathered SOURCE ids (not edge ids): attn needs only the source index.
__global__ void scatter_kernel(const int* __restrict__ tgt, const int* __restrict__ src,
                               const int* __restrict__ offsets,
                               int* __restrict__ cursor, int* __restrict__ srcs_sorted, int E) {
    int e = blockIdx.x * blockDim.x + threadIdx.x;
    if (e < E) {
        int t = tgt[e];
        int r = atomicAdd(&cursor[t], 1);
        srcs_sorted[offsets[t] + r] = src[e];
    }
}

// ---------------- split-precision hidden GEMM ----------------
// C = A[Mrows x 128] f32 @ BT^T + bias, computed as A_hi@B_hi + A_hi@B_lo + A_lo@B_hi
// (near-f32 accuracy). Output bf16, column-split: cols [0,512) -> outA (stride 512),
// cols [512,Ntot) -> outB (stride 128). 64x64 tile, BK=64 two-phase, 4 waves, 2x2 MFMA each.
__global__ __launch_bounds__(256, 4)
void gemm_hidden_kernel(const float* __restrict__ A,
                        const unsigned short* __restrict__ BThi,
                        const unsigned short* __restrict__ BTlo,
                        const float* __restrict__ bias,
                        unsigned short* __restrict__ outA, unsigned short* __restrict__ outB,
                        int Mrows, int Ntot) {
    __shared__ unsigned short Ahi[64 * 72], Alo[64 * 72];  // stride 72 shorts = 144 B (16B-mult)
    __shared__ unsigned short Bhi[64 * 72], Blo[64 * 72];
    int tid = threadIdx.x;
    int row0 = blockIdx.y * 64, col0 = blockIdx.x * 64;
    int wid = tid >> 6, lane = tid & 63;
    int wm = (wid >> 1) * 32, wn = (wid & 1) * 32;
    int g = lane >> 4, r16 = lane & 15;

    f32x4 acc00 = {0.f, 0.f, 0.f, 0.f}, acc01 = acc00, acc10 = acc00, acc11 = acc00;

    for (int kb = 0; kb < 128; kb += 64) {
        // Stage A: 64 rows x 64 k = 512 chunks of 8 floats, 2 per thread; split hi/lo.
#pragma unroll
        for (int l = 0; l < 2; ++l) {
            int idx = l * 256 + tid;
            int r = idx >> 3, c8 = idx & 7;
            int row = row0 + r;
            float4 v0 = make_float4(0.f, 0.f, 0.f, 0.f), v1 = v0;
            if (row < Mrows) {
                v0 = *(const float4*)(A + (size_t)row * 128 + kb + c8 * 8);
                v1 = *(const float4*)(A + (size_t)row * 128 + kb + c8 * 8 + 4);
            }
            ushort4 h0, h1, o0, o1;
            h0.x = f2bf(v0.x); o0.x = f2bf(v0.x - bf2f(h0.x));
            h0.y = f2bf(v0.y); o0.y = f2bf(v0.y - bf2f(h0.y));
            h0.z = f2bf(v0.z); o0.z = f2bf(v0.z - bf2f(h0.z));
            h0.w = f2bf(v0.w); o0.w = f2bf(v0.w - bf2f(h0.w));
            h1.x = f2bf(v1.x); o1.x = f2bf(v1.x - bf2f(h1.x));
            h1.y = f2bf(v1.y); o1.y = f2bf(v1.y - bf2f(h1.y));
            h1.z = f2bf(v1.z); o1.z = f2bf(v1.z - bf2f(h1.z));
            h1.w = f2bf(v1.w); o1.w = f2bf(v1.w - bf2f(h1.w));
            *(ushort4*)(&Ahi[r * 72 + c8 * 8])     = h0;
            *(ushort4*)(&Ahi[r * 72 + c8 * 8 + 4]) = h1;
            *(ushort4*)(&Alo[r * 72 + c8 * 8])     = o0;
            *(ushort4*)(&Alo[r * 72 + c8 * 8 + 4]) = o1;
        }
        // Stage B hi/lo: 64 n-rows x 64 k, 2 chunks per thread each.
#pragma unroll
        for (int l = 0; l < 2; ++l) {
            int idx = l * 256 + tid;
            int r = idx >> 3, c8 = idx & 7;
            uint4 vh = *(const uint4*)(BThi + (size_t)(col0 + r) * 128 + kb + c8 * 8);
            uint4 vl = *(const uint4*)(BTlo + (size_t)(col0 + r) * 128 + kb + c8 * 8);
            *(uint4*)(&Bhi[r * 72 + c8 * 8]) = vh;
            *(uint4*)(&Blo[r * 72 + c8 * 8]) = vl;
        }
        __syncthreads();

#pragma unroll
        for (int kk = 0; kk < 2; ++kk) {
            int k0 = kk * 32 + g * 8;
            bf16x8 ah0 = *(const bf16x8*)(&Ahi[(wm + r16) * 72 + k0]);
            bf16x8 ah1 = *(const bf16x8*)(&Ahi[(wm + 16 + r16) * 72 + k0]);
            bf16x8 al0 = *(const bf16x8*)(&Alo[(wm + r16) * 72 + k0]);
            bf16x8 al1 = *(const bf16x8*)(&Alo[(wm + 16 + r16) * 72 + k0]);
            bf16x8 bh0 = *(const bf16x8*)(&Bhi[(wn + r16) * 72 + k0]);
            bf16x8 bh1 = *(const bf16x8*)(&Bhi[(wn + 16 + r16) * 72 + k0]);
            bf16x8 bl0 = *(const bf16x8*)(&Blo[(wn + r16) * 72 + k0]);
            bf16x8 bl1 = *(const bf16x8*)(&Blo[(wn + 16 + r16) * 72 + k0]);
            acc00 = __builtin_amdgcn_mfma_f32_16x16x32_bf16(ah0, bh0, acc00, 0, 0, 0);
            acc00 = __builtin_amdgcn_mfma_f32_16x16x32_bf16(ah0, bl0, acc00, 0, 0, 0);
            acc00 = __builtin_amdgcn_mfma_f32_16x16x32_bf16(al0, bh0, acc00, 0, 0, 0);
            acc01 = __builtin_amdgcn_mfma_f32_16x16x32_bf16(ah0, bh1, acc01, 0, 0, 0);
            acc01 = __builtin_amdgcn_mfma_f32_16x16x32_bf16(ah0, bl1, acc01, 0, 0, 0);
            acc01 = __builtin_amdgcn_mfma_f32_16x16x32_bf16(al0, bh1, acc01, 0, 0, 0);
            acc10 = __builtin_amdgcn_mfma_f32_16x16x32_bf16(ah1, bh0, acc10, 0, 0, 0);
            acc10 = __builtin_amdgcn_mfma_f32_16x16x32_bf16(ah1, bl0, acc10, 0, 0, 0);
            acc10 = __builtin_amdgcn_mfma_f32_16x16x32_bf16(al1, bh0, acc10, 0, 0, 0);
            acc11 = __builtin_amdgcn_mfma_f32_16x16x32_bf16(ah1, bh1, acc11, 0, 0, 0);
            acc11 = __builtin_amdgcn_mfma_f32_16x16x32_bf16(ah1, bl1, acc11, 0, 0, 0);
            acc11 = __builtin_amdgcn_mfma_f32_16x16x32_bf16(al1, bh1, acc11, 0, 0, 0);
        }
        __syncthreads();
    }

    // Epilogue: C/D layout col = lane&15, row = (lane>>4)*4 + reg. bf16 stores, col-split.
    int c0 = col0 + wn + r16;
    int c1 = c0 + 16;
    float bv0 = bias[c0], bv1 = bias[c1];
#pragma unroll
    for (int i = 0; i < 4; ++i) {
        int rA = row0 + wm + g * 4 + i;
        int rB = rA + 16;
        if (rA < Mrows) {
            if (c0 < 512) outA[(size_t)rA * 512 + c0] = f2bf(acc00[i] + bv0);
            else          outB[(size_t)rA * 128 + (c0 - 512)] = f2bf(acc00[i] + bv0);
            if (c1 < 512) outA[(size_t)rA * 512 + c1] = f2bf(acc01[i] + bv1);
            else          outB[(size_t)rA * 128 + (c1 - 512)] = f2bf(acc01[i] + bv1);
        }
        if (rB < Mrows) {
            if (c0 < 512) outA[(size_t)rB * 512 + c0] = f2bf(acc10[i] + bv0);
            else          outB[(size_t)rB * 128 + (c0 - 512)] = f2bf(acc10[i] + bv0);
            if (c1 < 512) outA[(size_t)rB * 512 + c1] = f2bf(acc11[i] + bv1);
            else          outB[(size_t)rB * 128 + (c1 - 512)] = f2bf(acc11[i] + bv1);
        }
    }
}

// ---------------- output GEMM: out[M x 128] f32 = agg(bf16) @ Wo_hi + bo ----------------
__global__ __launch_bounds__(256, 4)
void gemm_out_kernel(const unsigned short* __restrict__ A,
                     const unsigned short* __restrict__ BT,
                     const float* __restrict__ bias,
                     float* __restrict__ C, int Mrows, int Ntot) {
    __shared__ unsigned short As[64 * 136];
    __shared__ unsigned short Bs[64 * 136];
    int tid = threadIdx.x;
    int row0 = blockIdx.y * 64, col0 = blockIdx.x * 64;

#pragma unroll
    for (int l = 0; l < 4; ++l) {
        int idx = l * 256 + tid;
        int r = idx >> 4, c8 = idx & 15;
        int row = row0 + r;
        uint4 v = make_uint4(0, 0, 0, 0);
        if (row < Mrows) v = *(const uint4*)(A + (size_t)row * 128 + c8 * 8);
        *(uint4*)(&As[r * 136 + c8 * 8]) = v;
    }
#pragma unroll
    for (int l = 0; l < 4; ++l) {
        int idx = l * 256 + tid;
        int r = idx >> 4, c8 = idx & 15;
        uint4 v = *(const uint4*)(BT + (size_t)(col0 + r) * 128 + c8 * 8);
        *(uint4*)(&Bs[r * 136 + c8 * 8]) = v;
    }
    __syncthreads();

    int wid = tid >> 6, lane = tid & 63;
    int wm = (wid >> 1) * 32, wn = (wid & 1) * 32;
    int g = lane >> 4, r16 = lane & 15;

    f32x4 acc00 = {0.f, 0.f, 0.f, 0.f}, acc01 = acc00, acc10 = acc00, acc11 = acc00;

#pragma unroll
    for (int kk = 0; kk < 4; ++kk) {
        int k0 = kk * 32 + g * 8;
        bf16x8 a0 = *(const bf16x8*)(&As[(wm + r16) * 136 + k0]);
        bf16x8 a1 = *(const bf16x8*)(&As[(wm + 16 + r16) * 136 + k0]);
        bf16x8 b0 = *(const bf16x8*)(&Bs[(wn + r16) * 136 + k0]);
        bf16x8 b1 = *(const bf16x8*)(&Bs[(wn + 16 + r16) * 136 + k0]);
        acc00 = __builtin_amdgcn_mfma_f32_16x16x32_bf16(a0, b0, acc00, 0, 0, 0);
        acc01 = __builtin_amdgcn_mfma_f32_16x16x32_bf16(a0, b1, acc01, 0, 0, 0);
        acc10 = __builtin_amdgcn_mfma_f32_16x16x32_bf16(a1, b0, acc10, 0, 0, 0);
        acc11 = __builtin_amdgcn_mfma_f32_16x16x32_bf16(a1, b1, acc11, 0, 0, 0);
    }

    float bv0 = bias[col0 + wn + r16];
    float bv1 = bias[col0 + wn + 16 + r16];
#pragma unroll
    for (int i = 0; i < 4; ++i) {
        int rA = row0 + wm + g * 4 + i;
        int rB = rA + 16;
        if (rA < Mrows) {
            C[(size_t)rA * Ntot + col0 + wn + r16]      = acc00[i] + bv0;
            C[(size_t)rA * Ntot + col0 + wn + 16 + r16] = acc01[i] + bv1;
        }
        if (rB < Mrows) {
            C[(size_t)rB * Ntot + col0 + wn + r16]      = acc10[i] + bv0;
            C[(size_t)rB * Ntot + col0 + wn + 16 + r16] = acc11[i] + bv1;
        }
    }
}

// ---------------- fused per-target online-softmax attention + aggregation ----------------
// One wave per target; 2-edge unrolled online softmax. Lane l: hidden dims [8l,8l+8),
// output dims {2l,2l+1}, both in head l>>4 (16-lane butterfly reduce).
// Hs [N,512] bf16, Ht [M,512] bf16, Hm [N,128] bf16, agg [M,128] bf16.
__global__ __launch_bounds__(256)
void attn_kernel(const unsigned short* __restrict__ Hs, const unsigned short* __restrict__ Ht,
                 const unsigned short* __restrict__ Hm, const float* __restrict__ attn_w,
                 const int* __restrict__ offsets, const int* __restrict__ srcs,
                 unsigned short* __restrict__ agg, int M) {
    int wave = threadIdx.x >> 6;
    int lane = threadIdx.x & 63;
    int t = blockIdx.x * 4 + wave;
    if (t >= M) return;

    int j0 = lane << 3;
    float ht[8];
    {
        uint4 h = *(const uint4*)(Ht + (size_t)t * 512 + j0);
        unpack2(h.x, ht[0], ht[1]); unpack2(h.y, ht[2], ht[3]);
        unpack2(h.z, ht[4], ht[5]); unpack2(h.w, ht[6], ht[7]);
    }
    float aw[8];
    {
        float4 a0 = *(const float4*)(attn_w + j0);
        float4 a1 = *(const float4*)(attn_w + j0 + 4);
        aw[0] = a0.x; aw[1] = a0.y; aw[2] = a0.z; aw[3] = a0.w;
        aw[4] = a1.x; aw[5] = a1.y; aw[6] = a1.z; aw[7] = a1.w;
    }

    int off = offsets[t];
    int end = offsets[t + 1];

    float m = -INFINITY, den = 0.f, acc0 = 0.f, acc1 = 0.f;

    int i = off;
    for (; i + 1 < end; i += 2) {
        int s0 = srcs[i], s1 = srcs[i + 1];
        uint4 ha = *(const uint4*)(Hs + (size_t)s0 * 512 + j0);
        uint4 hb = *(const uint4*)(Hs + (size_t)s1 * 512 + j0);
        unsigned ma = *(const unsigned*)(Hm + (size_t)s0 * 128 + (lane << 1));
        unsigned mb = *(const unsigned*)(Hm + (size_t)s1 * 128 + (lane << 1));
        float x0, x1, q0, q1;
        unpack2(ha.x, x0, x1); q0  = gelu_f(x0 + ht[0]) * aw[0] + gelu_f(x1 + ht[1]) * aw[1];
        unpack2(ha.y, x0, x1); q0 += gelu_f(x0 + ht[2]) * aw[2] + gelu_f(x1 + ht[3]) * aw[3];
        unpack2(ha.z, x0, x1); q0 += gelu_f(x0 + ht[4]) * aw[4] + gelu_f(x1 + ht[5]) * aw[5];
        unpack2(ha.w, x0, x1); q0 += gelu_f(x0 + ht[6]) * aw[6] + gelu_f(x1 + ht[7]) * aw[7];
        unpack2(hb.x, x0, x1); q1  = gelu_f(x0 + ht[0]) * aw[0] + gelu_f(x1 + ht[1]) * aw[1];
        unpack2(hb.y, x0, x1); q1 += gelu_f(x0 + ht[2]) * aw[2] + gelu_f(x1 + ht[3]) * aw[3];
        unpack2(hb.z, x0, x1); q1 += gelu_f(x0 + ht[4]) * aw[4] + gelu_f(x1 + ht[5]) * aw[5];
        unpack2(hb.w, x0, x1); q1 += gelu_f(x0 + ht[6]) * aw[6] + gelu_f(x1 + ht[7]) * aw[7];
        q0 += __shfl_xor(q0, 1); q1 += __shfl_xor(q1, 1);
        q0 += __shfl_xor(q0, 2); q1 += __shfl_xor(q1, 2);
        q0 += __shfl_xor(q0, 4); q1 += __shfl_xor(q1, 4);
        q0 += __shfl_xor(q0, 8); q1 += __shfl_xor(q1, 8);

        float m0x, m0y, m1x, m1y;
        unpack2(ma, m0x, m0y);
        unpack2(mb, m1x, m1y);

        float nm = fmaxf(m, fmaxf(q0, q1));
        float sc = __expf(m - nm);
        float p0 = __expf(q0 - nm);
        float p1 = __expf(q1 - nm);
        den  = den  * sc + p0 + p1;
        acc0 = fmaf(p1, m1x, fmaf(p0, m0x, acc0 * sc));
        acc1 = fmaf(p1, m1y, fmaf(p0, m0y, acc1 * sc));
        m = nm;
    }
    if (i < end) {
        int s0 = srcs[i];
        uint4 ha = *(const uint4*)(Hs + (size_t)s0 * 512 + j0);
        unsigned ma = *(const unsigned*)(Hm + (size_t)s0 * 128 + (lane << 1));
        float x0, x1, q0;
        unpack2(ha.x, x0, x1); q0  = gelu_f(x0 + ht[0]) * aw[0] + gelu_f(x1 + ht[1]) * aw[1];
        unpack2(ha.y, x0, x1); q0 += gelu_f(x0 + ht[2]) * aw[2] + gelu_f(x1 + ht[3]) * aw[3];
        unpack2(ha.z, x0, x1); q0 += gelu_f(x0 + ht[4]) * aw[4] + gelu_f(x1 + ht[5]) * aw[5];
        unpack2(ha.w, x0, x1); q0 += gelu_f(x0 + ht[6]) * aw[6] + gelu_f(x1 + ht[7]) * aw[7];
        q0 += __shfl_xor(q0, 1);
        q0 += __shfl_xor(q0, 2);
        q0 += __shfl_xor(q0, 4);
        q0 += __shfl_xor(q0, 8);
        float m0x, m0y;
        unpack2(ma, m0x, m0y);
        float nm = fmaxf(m, q0);
        float sc = __expf(m - nm);
        float p0 = __expf(q0 - nm);
        den  = den  * sc + p0;
        acc0 = fmaf(p0, m0x, acc0 * sc);
        acc1 = fmaf(p0, m0y, acc1 * sc);
    }
    float r = (end > off) ? __builtin_amdgcn_rcpf(den) : 0.0f;
    ushort2 o;
    o.x = f2bf(acc0 * r);
    o.y = f2bf(acc1 * r);
    *(ushort2*)(agg + (size_t)t * 128 + (lane << 1)) = o;
}

extern "C" void kernel_launch(void* const* d_in, const int* in_sizes, int n_in,
                              void* d_out, int out_size, void* d_ws, size_t ws_size,
                              hipStream_t stream) {
    const float* src_f  = (const float*)d_in[0];
    const float* tgt_f  = (const float*)d_in[1];
    const int*   e_tgt  = (const int*)d_in[2];
    const int*   e_src  = (const int*)d_in[3];
    const float* Ws     = (const float*)d_in[4];
    const float* bs     = (const float*)d_in[5];
    const float* Wt     = (const float*)d_in[6];
    const float* bt     = (const float*)d_in[7];
    const float* attn_w = (const float*)d_in[8];
    const float* Wm     = (const float*)d_in[9];
    const float* bm     = (const float*)d_in[10];
    const float* Wo     = (const float*)d_in[11];
    const float* bo     = (const float*)d_in[12];

    int N = in_sizes[0] / 128;
    int M = in_sizes[1] / 128;
    int E = in_sizes[2];

    char* ws = (char*)d_ws;
    size_t woff = 0;
    auto alloc = [&](size_t bytes) -> void* {
        void* p = ws + woff;
        woff += ((bytes + 255) / 256) * 256;
        return p;
    };
    // Total ~131 MB
    unsigned short* Hs       = (unsigned short*)alloc((size_t)N * 512 * 2);
    unsigned short* Ht       = (unsigned short*)alloc((size_t)M * 512 * 2);
    unsigned short* Hm       = (unsigned short*)alloc((size_t)N * 128 * 2);
    unsigned short* agg_bf   = (unsigned short*)alloc((size_t)M * 128 * 2);
    unsigned short* WThi     = (unsigned short*)alloc((size_t)1280 * 128 * 2);
    unsigned short* WTlo     = (unsigned short*)alloc((size_t)1280 * 128 * 2);
    float*          bias_cat = (float*)alloc(640 * 4);
    int*            counts   = (int*)alloc((size_t)M * 4);
    int*            cursor   = (int*)alloc((size_t)M * 4);
    int*            offsets  = (int*)alloc((size_t)(M + 1) * 4);
    int*            srcs     = (int*)alloc((size_t)E * 4);

    hipMemsetAsync(counts, 0, (size_t)M * 4, stream);
    hipMemsetAsync(cursor, 0, (size_t)M * 4, stream);

    const int tb = 256;
    // CSR build
    hist_kernel<<<(E + tb - 1) / tb, tb, 0, stream>>>(e_tgt, counts, E);
    scan_kernel<<<1, 1024, 0, stream>>>(counts, offsets, M);
    scatter_kernel<<<(E + tb - 1) / tb, tb, 0, stream>>>(e_tgt, e_src, offsets, cursor, srcs, E);

    // Weight prep (hi/lo split)
    prep_weights_kernel<<<1280, 128, 0, stream>>>(Ws, Wm, Wt, Wo, bs, bm, WThi, WTlo, bias_cat);

    // [Hs|Hm] = src @ [Ws|Wm] + [bs|bm]  (split-precision, bf16 out, col-split at 512)
    dim3 gs(640 / 64, (N + 63) / 64);
    gemm_hidden_kernel<<<gs, 256, 0, stream>>>(src_f, WThi, WTlo, bias_cat, Hs, Hm, N, 640);
    // Ht = tgt @ Wt + bt
    dim3 gt(512 / 64, (M + 63) / 64);
    gemm_hidden_kernel<<<gt, 256, 0, stream>>>(tgt_f, WThi + (size_t)640 * 128,
                                               WTlo + (size_t)640 * 128, bt, Ht, nullptr, M, 512);

    attn_kernel<<<(M + 3) / 4, 256, 0, stream>>>(Hs, Ht, Hm, attn_w, offsets, srcs, agg_bf, M);

    // out = agg @ Wo + bo
    dim3 go(128 / 64, (M + 63) / 64);
    gemm_out_kernel<<<go, 256, 0, stream>>>(agg_bf, WThi + (size_t)1152 * 128, bo,
                                            (float*)d_out, M, 128);
}

// Round 6
// 372.719 us; speedup vs baseline: 13.1596x; 1.1836x over previous
//
#include <hip/hip_runtime.h>
#include <math.h>

// InterRankAttention — R6: pk-packed attention math (f32x2 -> v_pk_*_f32),
// exp2-domain gelu/softmax (no stray muls before v_exp), 4-edge unroll;
// pre-split bf16 hi/lo feature buffers (pure-copy GEMM staging); merged
// hidden GEMM dispatch; parallel 3-pass CSR scan.

typedef __bf16 bf16x8 __attribute__((ext_vector_type(8)));
typedef float  f32x4  __attribute__((ext_vector_type(4)));
typedef float  f32x2  __attribute__((ext_vector_type(2)));

__device__ __forceinline__ unsigned short f2bf(float x) {
    unsigned u = __float_as_uint(x);
    u += 0x7FFFu + ((u >> 16) & 1u);   // round-to-nearest-even
    return (unsigned short)(u >> 16);
}
__device__ __forceinline__ float bf2f(unsigned short b) {
    return __uint_as_float(((unsigned)b) << 16);
}
__device__ __forceinline__ f32x2 up2(unsigned u) {   // dword = 2 bf16 -> f32x2
    f32x2 r;
    r.x = __uint_as_float(u << 16);
    r.y = __uint_as_float(u & 0xFFFF0000u);
    return r;
}
__device__ __forceinline__ float exp2_fast(float x) {
#if __has_builtin(__builtin_amdgcn_exp2f)
    return __builtin_amdgcn_exp2f(x);
#else
    return exp2f(x);
#endif
}

// gelu in exp2 domain: gelu(x) = x - x/(2^(C1*x + C2*x^3) + 1)
// C1 = 1.5957691216*log2(e), C2 = 0.0713548163*log2(e)
__device__ __forceinline__ f32x2 gelu2(f32x2 v) {
    f32x2 v2 = v * v;
    f32x2 u  = v * (v2 * 0.10294355f + 2.30220820f);
    f32x2 e;
    e.x = exp2_fast(u.x);
    e.y = exp2_fast(u.y);
    f32x2 r;
    r.x = __builtin_amdgcn_rcpf(e.x + 1.0f);
    r.y = __builtin_amdgcn_rcpf(e.y + 1.0f);
    return v - v * r;
}

// logit (pre-scaled by log2e via aw): sum over this lane's 8 dims
__device__ __forceinline__ float edge_logit(uint4 h,
    f32x2 ht0, f32x2 ht1, f32x2 ht2, f32x2 ht3,
    f32x2 aw0, f32x2 aw1, f32x2 aw2, f32x2 aw3) {
    f32x2 qv = gelu2(up2(h.x) + ht0) * aw0;
    qv += gelu2(up2(h.y) + ht1) * aw1;
    qv += gelu2(up2(h.z) + ht2) * aw2;
    qv += gelu2(up2(h.w) + ht3) * aw3;
    return qv.x + qv.y;
}

// ---------------- feature cast: f32 -> bf16 hi/lo ----------------
__global__ __launch_bounds__(256)
void cast_split_kernel(const float* __restrict__ src, const float* __restrict__ tgt,
                       unsigned short* __restrict__ shi, unsigned short* __restrict__ slo,
                       unsigned short* __restrict__ thi, unsigned short* __restrict__ tlo,
                       int n4src, int n4tot) {
    int i = blockIdx.x * blockDim.x + threadIdx.x;
    if (i >= n4tot) return;
    const float* in; unsigned short *hi, *lo; int j;
    if (i < n4src) { in = src; hi = shi; lo = slo; j = i; }
    else           { in = tgt; hi = thi; lo = tlo; j = i - n4src; }
    float4 v = *(const float4*)(in + (size_t)j * 4);
    ushort4 h, l;
    h.x = f2bf(v.x); l.x = f2bf(v.x - bf2f(h.x));
    h.y = f2bf(v.y); l.y = f2bf(v.y - bf2f(h.y));
    h.z = f2bf(v.z); l.z = f2bf(v.z - bf2f(h.z));
    h.w = f2bf(v.w); l.w = f2bf(v.w - bf2f(h.w));
    *(ushort4*)(hi + (size_t)j * 4) = h;
    *(ushort4*)(lo + (size_t)j * 4) = l;
}

// ---------------- weight prep: WT_hi/WT_lo [1280][128] bf16 + bias_cat[640] ----------------
// rows 0..511 = Ws^T, 512..639 = Wm^T, 640..1151 = Wt^T, 1152..1279 = Wo^T
__global__ __launch_bounds__(128)
void prep_weights_kernel(const float* __restrict__ Ws, const float* __restrict__ Wm,
                         const float* __restrict__ Wt, const float* __restrict__ Wo,
                         const float* __restrict__ bs, const float* __restrict__ bm,
                         unsigned short* __restrict__ WThi, unsigned short* __restrict__ WTlo,
                         float* __restrict__ bias_cat) {
    int n = blockIdx.x, k = threadIdx.x;
    float w;
    if      (n < 512)  w = Ws[(size_t)k * 512 + n];
    else if (n < 640)  w = Wm[(size_t)k * 128 + (n - 512)];
    else if (n < 1152) w = Wt[(size_t)k * 512 + (n - 640)];
    else               w = Wo[(size_t)k * 128 + (n - 1152)];
    unsigned short hi = f2bf(w);
    WThi[(size_t)n * 128 + k] = hi;
    WTlo[(size_t)n * 128 + k] = f2bf(w - bf2f(hi));
    if (k == 0 && n < 640) bias_cat[n] = (n < 512) ? bs[n] : bm[n - 512];
}

// ---------------- CSR build ----------------
__global__ void hist_kernel(const int* __restrict__ tgt, int* __restrict__ counts, int E) {
    int e = blockIdx.x * blockDim.x + threadIdx.x;
    if (e < E) atomicAdd(&counts[tgt[e]], 1);
}

// 3-pass parallel exclusive scan over counts[M] (M <= 64*1024)
__global__ __launch_bounds__(256)
void scan_partial_kernel(const int* __restrict__ counts, int* __restrict__ partials, int M) {
    __shared__ int sdata[256];
    int b = blockIdx.x, tid = threadIdx.x;
    int base = b * 1024 + tid * 4;
    int s = 0;
#pragma unroll
    for (int k = 0; k < 4; ++k) { int idx = base + k; if (idx < M) s += counts[idx]; }
    sdata[tid] = s; __syncthreads();
    for (int d = 128; d > 0; d >>= 1) {
        if (tid < d) sdata[tid] += sdata[tid + d];
        __syncthreads();
    }
    if (tid == 0) partials[b] = sdata[0];
}

__global__ __launch_bounds__(64)
void scan_partials_kernel(const int* __restrict__ partials, int* __restrict__ pbase,
                          int* __restrict__ offsets, int P, int M) {
    int lane = threadIdx.x;
    int own = (lane < P) ? partials[lane] : 0;
    int v = own;
    for (int d = 1; d < 64; d <<= 1) {
        int o = __shfl_up(v, d);
        if (lane >= d) v += o;
    }
    if (lane < P) pbase[lane] = v - own;   // exclusive prefix of partials
    if (lane == 63) offsets[M] = v;        // total = E
}

__global__ __launch_bounds__(256)
void scan_final_kernel(const int* __restrict__ counts, const int* __restrict__ pbase,
                       int* __restrict__ offsets, int M) {
    __shared__ int sdata[256];
    int b = blockIdx.x, tid = threadIdx.x;
    int base = b * 1024 + tid * 4;
    int c0 = 0, c1 = 0, c2 = 0, c3 = 0;
    if (base + 0 < M) c0 = counts[base + 0];
    if (base + 1 < M) c1 = counts[base + 1];
    if (base + 2 < M) c2 = counts[base + 2];
    if (base + 3 < M) c3 = counts[base + 3];
    int s = c0 + c1 + c2 + c3;
    sdata[tid] = s; __syncthreads();
    int v = s;
    for (int d = 1; d < 256; d <<= 1) {
        int o = (tid >= d) ? sdata[tid - d] : 0;
        __syncthreads();
        v += o;
        sdata[tid] = v;
        __syncthreads();
    }
    int ex = pbase[b] + v - s;  // block base + thread-exclusive
    if (base + 0 < M) offsets[base + 0] = ex;
    if (base + 1 < M) offsets[base + 1] = ex + c0;
    if (base + 2 < M) offsets[base + 2] = ex + c0 + c1;
    if (base + 3 < M) offsets[base + 3] = ex + c0 + c1 + c2;
}

// Writes pre-gathered SOURCE ids grouped by target.
__global__ void scatter_kernel(const int* __restrict__ tgt, const int* __restrict__ src,
                               const int* __restrict__ offsets,
                               int* __restrict__ cursor, int* __restrict__ srcs_sorted, int E) {
    int e = blockIdx.x * blockDim.x + threadIdx.x;
    if (e < E) {
        int t = tgt[e];
        int r = atomicAdd(&cursor[t], 1);
        srcs_sorted[offsets[t] + r] = src[e];
    }
}

// ---------------- merged split-precision hidden GEMM ----------------
// blockIdx.x < 10: [Hs|Hm] = src @ [Ws|Wm] + [bs|bm]  (cols 0..639, split at 512)
// blockIdx.x >= 10: Ht = tgt @ Wt + bt                (cols 0..511)
// A given as pre-split bf16 hi/lo [rows][128]. 3-MFMA split product per acc.
__global__ __launch_bounds__(256, 4)
void gemm_hidden_kernel(const unsigned short* __restrict__ shi, const unsigned short* __restrict__ slo,
                        const unsigned short* __restrict__ thi, const unsigned short* __restrict__ tlo,
                        const unsigned short* __restrict__ WThi, const unsigned short* __restrict__ WTlo,
                        const float* __restrict__ bias_cat, const float* __restrict__ bt,
                        unsigned short* __restrict__ Hs, unsigned short* __restrict__ Hm,
                        unsigned short* __restrict__ Ht, int N, int M) {
    __shared__ unsigned short Ahi[64 * 72], Alo[64 * 72];
    __shared__ unsigned short Bhi[64 * 72], Blo[64 * 72];
    int bx = blockIdx.x;
    bool side1 = bx >= 10;
    const unsigned short* Ahi_g = side1 ? thi : shi;
    const unsigned short* Alo_g = side1 ? tlo : slo;
    int rows = side1 ? M : N;
    int row0 = blockIdx.y * 64;
    if (row0 >= rows) return;
    int colL = side1 ? (bx - 10) * 64 : bx * 64;   // logical output col
    int colW = side1 ? 640 + colL : colL;          // row in WT
    const float* bias = side1 ? bt : bias_cat;

    int tid = threadIdx.x;
    int wid = tid >> 6, lane = tid & 63;
    int wm = (wid >> 1) * 32, wn = (wid & 1) * 32;
    int g = lane >> 4, r16 = lane & 15;

    f32x4 acc00 = {0.f, 0.f, 0.f, 0.f}, acc01 = acc00, acc10 = acc00, acc11 = acc00;

    for (int kb = 0; kb < 128; kb += 64) {
#pragma unroll
        for (int l = 0; l < 2; ++l) {
            int idx = l * 256 + tid;
            int r = idx >> 3, c8 = idx & 7;
            int row = row0 + r;
            uint4 vh = make_uint4(0, 0, 0, 0), vl = vh;
            if (row < rows) {
                vh = *(const uint4*)(Ahi_g + (size_t)row * 128 + kb + c8 * 8);
                vl = *(const uint4*)(Alo_g + (size_t)row * 128 + kb + c8 * 8);
            }
            *(uint4*)(&Ahi[r * 72 + c8 * 8]) = vh;
            *(uint4*)(&Alo[r * 72 + c8 * 8]) = vl;
            uint4 wh = *(const uint4*)(WThi + (size_t)(colW + r) * 128 + kb + c8 * 8);
            uint4 wl = *(const uint4*)(WTlo + (size_t)(colW + r) * 128 + kb + c8 * 8);
            *(uint4*)(&Bhi[r * 72 + c8 * 8]) = wh;
            *(uint4*)(&Blo[r * 72 + c8 * 8]) = wl;
        }
        __syncthreads();

#pragma unroll
        for (int kk = 0; kk < 2; ++kk) {
            int k0 = kk * 32 + g * 8;
            bf16x8 ah0 = *(const bf16x8*)(&Ahi[(wm + r16) * 72 + k0]);
            bf16x8 ah1 = *(const bf16x8*)(&Ahi[(wm + 16 + r16) * 72 + k0]);
            bf16x8 al0 = *(const bf16x8*)(&Alo[(wm + r16) * 72 + k0]);
            bf16x8 al1 = *(const bf16x8*)(&Alo[(wm + 16 + r16) * 72 + k0]);
            bf16x8 bh0 = *(const bf16x8*)(&Bhi[(wn + r16) * 72 + k0]);
            bf16x8 bh1 = *(const bf16x8*)(&Bhi[(wn + 16 + r16) * 72 + k0]);
            bf16x8 bl0 = *(const bf16x8*)(&Blo[(wn + r16) * 72 + k0]);
            bf16x8 bl1 = *(const bf16x8*)(&Blo[(wn + 16 + r16) * 72 + k0]);
            acc00 = __builtin_amdgcn_mfma_f32_16x16x32_bf16(ah0, bh0, acc00, 0, 0, 0);
            acc00 = __builtin_amdgcn_mfma_f32_16x16x32_bf16(ah0, bl0, acc00, 0, 0, 0);
            acc00 = __builtin_amdgcn_mfma_f32_16x16x32_bf16(al0, bh0, acc00, 0, 0, 0);
            acc01 = __builtin_amdgcn_mfma_f32_16x16x32_bf16(ah0, bh1, acc01, 0, 0, 0);
            acc01 = __builtin_amdgcn_mfma_f32_16x16x32_bf16(ah0, bl1, acc01, 0, 0, 0);
            acc01 = __builtin_amdgcn_mfma_f32_16x16x32_bf16(al0, bh1, acc01, 0, 0, 0);
            acc10 = __builtin_amdgcn_mfma_f32_16x16x32_bf16(ah1, bh0, acc10, 0, 0, 0);
            acc10 = __builtin_amdgcn_mfma_f32_16x16x32_bf16(ah1, bl0, acc10, 0, 0, 0);
            acc10 = __builtin_amdgcn_mfma_f32_16x16x32_bf16(al1, bh0, acc10, 0, 0, 0);
            acc11 = __builtin_amdgcn_mfma_f32_16x16x32_bf16(ah1, bh1, acc11, 0, 0, 0);
            acc11 = __builtin_amdgcn_mfma_f32_16x16x32_bf16(ah1, bl1, acc11, 0, 0, 0);
            acc11 = __builtin_amdgcn_mfma_f32_16x16x32_bf16(al1, bh1, acc11, 0, 0, 0);
        }
        __syncthreads();
    }

    // C/D layout: col = lane&15, row = (lane>>4)*4 + reg
    int c0 = colL + wn + r16;
    int c1 = c0 + 16;
    float bv0 = bias[c0], bv1 = bias[c1];
#pragma unroll
    for (int i = 0; i < 4; ++i) {
        int rA = row0 + wm + g * 4 + i;
        int rB = rA + 16;
        if (rA < rows) {
            float o0 = acc00[i] + bv0, o1 = acc01[i] + bv1;
            if (side1) {
                Ht[(size_t)rA * 512 + c0] = f2bf(o0);
                Ht[(size_t)rA * 512 + c1] = f2bf(o1);
            } else {
                if (c0 < 512) Hs[(size_t)rA * 512 + c0] = f2bf(o0);
                else          Hm[(size_t)rA * 128 + (c0 - 512)] = f2bf(o0);
                if (c1 < 512) Hs[(size_t)rA * 512 + c1] = f2bf(o1);
                else          Hm[(size_t)rA * 128 + (c1 - 512)] = f2bf(o1);
            }
        }
        if (rB < rows) {
            float o0 = acc10[i] + bv0, o1 = acc11[i] + bv1;
            if (side1) {
                Ht[(size_t)rB * 512 + c0] = f2bf(o0);
                Ht[(size_t)rB * 512 + c1] = f2bf(o1);
            } else {
                if (c0 < 512) Hs[(size_t)rB * 512 + c0] = f2bf(o0);
                else          Hm[(size_t)rB * 128 + (c0 - 512)] = f2bf(o0);
                if (c1 < 512) Hs[(size_t)rB * 512 + c1] = f2bf(o1);
                else          Hm[(size_t)rB * 128 + (c1 - 512)] = f2bf(o1);
            }
        }
    }
}

// ---------------- output GEMM: out[M x 128] f32 = agg(bf16) @ Wo_hi + bo ----------------
__global__ __launch_bounds__(256, 4)
void gemm_out_kernel(const unsigned short* __restrict__ A,
                     const unsigned short* __restrict__ BT,
                     const float* __restrict__ bias,
                     float* __restrict__ C, int Mrows, int Ntot) {
    __shared__ unsigned short As[64 * 136];
    __shared__ unsigned short Bs[64 * 136];
    int tid = threadIdx.x;
    int row0 = blockIdx.y * 64, col0 = blockIdx.x * 64;

#pragma unroll
    for (int l = 0; l < 4; ++l) {
        int idx = l * 256 + tid;
        int r = idx >> 4, c8 = idx & 15;
        int row = row0 + r;
        uint4 v = make_uint4(0, 0, 0, 0);
        if (row < Mrows) v = *(const uint4*)(A + (size_t)row * 128 + c8 * 8);
        *(uint4*)(&As[r * 136 + c8 * 8]) = v;
    }
#pragma unroll
    for (int l = 0; l < 4; ++l) {
        int idx = l * 256 + tid;
        int r = idx >> 4, c8 = idx & 15;
        uint4 v = *(const uint4*)(BT + (size_t)(col0 + r) * 128 + c8 * 8);
        *(uint4*)(&Bs[r * 136 + c8 * 8]) = v;
    }
    __syncthreads();

    int wid = tid >> 6, lane = tid & 63;
    int wm = (wid >> 1) * 32, wn = (wid & 1) * 32;
    int g = lane >> 4, r16 = lane & 15;

    f32x4 acc00 = {0.f, 0.f, 0.f, 0.f}, acc01 = acc00, acc10 = acc00, acc11 = acc00;

#pragma unroll
    for (int kk = 0; kk < 4; ++kk) {
        int k0 = kk * 32 + g * 8;
        bf16x8 a0 = *(const bf16x8*)(&As[(wm + r16) * 136 + k0]);
        bf16x8 a1 = *(const bf16x8*)(&As[(wm + 16 + r16) * 136 + k0]);
        bf16x8 b0 = *(const bf16x8*)(&Bs[(wn + r16) * 136 + k0]);
        bf16x8 b1 = *(const bf16x8*)(&Bs[(wn + 16 + r16) * 136 + k0]);
        acc00 = __builtin_amdgcn_mfma_f32_16x16x32_bf16(a0, b0, acc00, 0, 0, 0);
        acc01 = __builtin_amdgcn_mfma_f32_16x16x32_bf16(a0, b1, acc01, 0, 0, 0);
        acc10 = __builtin_amdgcn_mfma_f32_16x16x32_bf16(a1, b0, acc10, 0, 0, 0);
        acc11 = __builtin_amdgcn_mfma_f32_16x16x32_bf16(a1, b1, acc11, 0, 0, 0);
    }

    float bv0 = bias[col0 + wn + r16];
    float bv1 = bias[col0 + wn + 16 + r16];
#pragma unroll
    for (int i = 0; i < 4; ++i) {
        int rA = row0 + wm + g * 4 + i;
        int rB = rA + 16;
        if (rA < Mrows) {
            C[(size_t)rA * Ntot + col0 + wn + r16]      = acc00[i] + bv0;
            C[(size_t)rA * Ntot + col0 + wn + 16 + r16] = acc01[i] + bv1;
        }
        if (rB < Mrows) {
            C[(size_t)rB * Ntot + col0 + wn + r16]      = acc10[i] + bv0;
            C[(size_t)rB * Ntot + col0 + wn + 16 + r16] = acc11[i] + bv1;
        }
    }
}

// ---------------- fused per-target online-softmax attention + aggregation ----------------
// One wave per target, 4-edge unroll. Lane l: hidden dims [8l,8l+8), output dims {2l,2l+1},
// both in head l>>4 (16-lane butterfly reduce). Logits kept in log2 domain (aw pre-scaled).
__global__ __launch_bounds__(256)
void attn_kernel(const unsigned short* __restrict__ Hs, const unsigned short* __restrict__ Ht,
                 const unsigned short* __restrict__ Hm, const float* __restrict__ attn_w,
                 const int* __restrict__ offsets, const int* __restrict__ srcs,
                 unsigned short* __restrict__ agg, int M) {
    int wave = threadIdx.x >> 6;
    int lane = threadIdx.x & 63;
    int t = blockIdx.x * 4 + wave;
    if (t >= M) return;

    int j0 = lane << 3;
    uint4 h = *(const uint4*)(Ht + (size_t)t * 512 + j0);
    f32x2 ht0 = up2(h.x), ht1 = up2(h.y), ht2 = up2(h.z), ht3 = up2(h.w);
    const float L2E = 1.4426950408889634f;
    float4 a0 = *(const float4*)(attn_w + j0);
    float4 a1 = *(const float4*)(attn_w + j0 + 4);
    f32x2 aw0 = {a0.x * L2E, a0.y * L2E};
    f32x2 aw1 = {a0.z * L2E, a0.w * L2E};
    f32x2 aw2 = {a1.x * L2E, a1.y * L2E};
    f32x2 aw3 = {a1.z * L2E, a1.w * L2E};

    int off = offsets[t];
    int end = offsets[t + 1];

    float m = -INFINITY, den = 0.f;
    f32x2 acc = {0.f, 0.f};
    int hm_off = lane << 1;

    int i = off;
    for (; i + 3 < end; i += 4) {
        int s0 = srcs[i], s1 = srcs[i + 1], s2 = srcs[i + 2], s3 = srcs[i + 3];
        uint4 hA = *(const uint4*)(Hs + (size_t)s0 * 512 + j0);
        uint4 hB = *(const uint4*)(Hs + (size_t)s1 * 512 + j0);
        uint4 hC = *(const uint4*)(Hs + (size_t)s2 * 512 + j0);
        uint4 hD = *(const uint4*)(Hs + (size_t)s3 * 512 + j0);
        unsigned mA = *(const unsigned*)(Hm + (size_t)s0 * 128 + hm_off);
        unsigned mB = *(const unsigned*)(Hm + (size_t)s1 * 128 + hm_off);
        unsigned mC = *(const unsigned*)(Hm + (size_t)s2 * 128 + hm_off);
        unsigned mD = *(const unsigned*)(Hm + (size_t)s3 * 128 + hm_off);
        float q0 = edge_logit(hA, ht0, ht1, ht2, ht3, aw0, aw1, aw2, aw3);
        float q1 = edge_logit(hB, ht0, ht1, ht2, ht3, aw0, aw1, aw2, aw3);
        float q2 = edge_logit(hC, ht0, ht1, ht2, ht3, aw0, aw1, aw2, aw3);
        float q3 = edge_logit(hD, ht0, ht1, ht2, ht3, aw0, aw1, aw2, aw3);
        q0 += __shfl_xor(q0, 1); q1 += __shfl_xor(q1, 1); q2 += __shfl_xor(q2, 1); q3 += __shfl_xor(q3, 1);
        q0 += __shfl_xor(q0, 2); q1 += __shfl_xor(q1, 2); q2 += __shfl_xor(q2, 2); q3 += __shfl_xor(q3, 2);
        q0 += __shfl_xor(q0, 4); q1 += __shfl_xor(q1, 4); q2 += __shfl_xor(q2, 4); q3 += __shfl_xor(q3, 4);
        q0 += __shfl_xor(q0, 8); q1 += __shfl_xor(q1, 8); q2 += __shfl_xor(q2, 8); q3 += __shfl_xor(q3, 8);

        float nm = fmaxf(fmaxf(fmaxf(q0, q1), fmaxf(q2, q3)), m);
        float sc = exp2_fast(m - nm);
        float p0 = exp2_fast(q0 - nm);
        float p1 = exp2_fast(q1 - nm);
        float p2 = exp2_fast(q2 - nm);
        float p3 = exp2_fast(q3 - nm);
        den = fmaf(den, sc, (p0 + p1) + (p2 + p3));
        acc = acc * sc;
        acc += p0 * up2(mA);
        acc += p1 * up2(mB);
        acc += p2 * up2(mC);
        acc += p3 * up2(mD);
        m = nm;
    }
    for (; i < end; ++i) {
        int s0 = srcs[i];
        uint4 hA = *(const uint4*)(Hs + (size_t)s0 * 512 + j0);
        unsigned mA = *(const unsigned*)(Hm + (size_t)s0 * 128 + hm_off);
        float q0 = edge_logit(hA, ht0, ht1, ht2, ht3, aw0, aw1, aw2, aw3);
        q0 += __shfl_xor(q0, 1);
        q0 += __shfl_xor(q0, 2);
        q0 += __shfl_xor(q0, 4);
        q0 += __shfl_xor(q0, 8);
        float nm = fmaxf(m, q0);
        float sc = exp2_fast(m - nm);
        float p0 = exp2_fast(q0 - nm);
        den = fmaf(den, sc, p0);
        acc = acc * sc + p0 * up2(mA);
        m = nm;
    }
    float r = (end > off) ? __builtin_amdgcn_rcpf(den) : 0.0f;
    ushort2 o;
    o.x = f2bf(acc.x * r);
    o.y = f2bf(acc.y * r);
    *(ushort2*)(agg + (size_t)t * 128 + hm_off) = o;
}

extern "C" void kernel_launch(void* const* d_in, const int* in_sizes, int n_in,
                              void* d_out, int out_size, void* d_ws, size_t ws_size,
                              hipStream_t stream) {
    const float* src_f  = (const float*)d_in[0];
    const float* tgt_f  = (const float*)d_in[1];
    const int*   e_tgt  = (const int*)d_in[2];
    const int*   e_src  = (const int*)d_in[3];
    const float* Ws     = (const float*)d_in[4];
    const float* bs     = (const float*)d_in[5];
    const float* Wt     = (const float*)d_in[6];
    const float* bt     = (const float*)d_in[7];
    const float* attn_w = (const float*)d_in[8];
    const float* Wm     = (const float*)d_in[9];
    const float* bm     = (const float*)d_in[10];
    const float* Wo     = (const float*)d_in[11];
    const float* bo     = (const float*)d_in[12];

    int N = in_sizes[0] / 128;
    int M = in_sizes[1] / 128;
    int E = in_sizes[2];

    char* ws = (char*)d_ws;
    size_t woff = 0;
    auto alloc = [&](size_t bytes) -> void* {
        void* p = ws + woff;
        woff += ((bytes + 255) / 256) * 256;
        return p;
    };
    // ~182 MB total
    unsigned short* Hs       = (unsigned short*)alloc((size_t)N * 512 * 2);
    unsigned short* Ht       = (unsigned short*)alloc((size_t)M * 512 * 2);
    unsigned short* Hm       = (unsigned short*)alloc((size_t)N * 128 * 2);
    unsigned short* agg_bf   = (unsigned short*)alloc((size_t)M * 128 * 2);
    unsigned short* shi      = (unsigned short*)alloc((size_t)N * 128 * 2);
    unsigned short* slo      = (unsigned short*)alloc((size_t)N * 128 * 2);
    unsigned short* thi      = (unsigned short*)alloc((size_t)M * 128 * 2);
    unsigned short* tlo      = (unsigned short*)alloc((size_t)M * 128 * 2);
    unsigned short* WThi     = (unsigned short*)alloc((size_t)1280 * 128 * 2);
    unsigned short* WTlo     = (unsigned short*)alloc((size_t)1280 * 128 * 2);
    float*          bias_cat = (float*)alloc(640 * 4);
    int*            counts   = (int*)alloc((size_t)M * 4);
    int*            cursor   = (int*)alloc((size_t)M * 4);
    int*            offsets  = (int*)alloc((size_t)(M + 1) * 4);
    int*            srcs     = (int*)alloc((size_t)E * 4);
    int*            partials = (int*)alloc(64 * 4);
    int*            pbase    = (int*)alloc(64 * 4);

    hipMemsetAsync(counts, 0, (size_t)M * 4, stream);
    hipMemsetAsync(cursor, 0, (size_t)M * 4, stream);

    const int tb = 256;
    int P = (M + 1023) / 1024;  // <= 64 for M <= 65536

    // CSR build
    hist_kernel<<<(E + tb - 1) / tb, tb, 0, stream>>>(e_tgt, counts, E);
    scan_partial_kernel<<<P, 256, 0, stream>>>(counts, partials, M);
    scan_partials_kernel<<<1, 64, 0, stream>>>(partials, pbase, offsets, P, M);
    scan_final_kernel<<<P, 256, 0, stream>>>(counts, pbase, offsets, M);
    scatter_kernel<<<(E + tb - 1) / tb, tb, 0, stream>>>(e_tgt, e_src, offsets, cursor, srcs, E);

    // Feature hi/lo split + weight prep
    int n4src = N * 32, n4tot = (N + M) * 32;
    cast_split_kernel<<<(n4tot + tb - 1) / tb, tb, 0, stream>>>(src_f, tgt_f, shi, slo, thi, tlo,
                                                               n4src, n4tot);
    prep_weights_kernel<<<1280, 128, 0, stream>>>(Ws, Wm, Wt, Wo, bs, bm, WThi, WTlo, bias_cat);

    // Merged hidden GEMMs: x<10 -> [Hs|Hm], x>=10 -> Ht
    int rowsMax = (N > M) ? N : M;
    dim3 gh(18, (rowsMax + 63) / 64);
    gemm_hidden_kernel<<<gh, 256, 0, stream>>>(shi, slo, thi, tlo, WThi, WTlo, bias_cat, bt,
                                               Hs, Hm, Ht, N, M);

    attn_kernel<<<(M + 3) / 4, 256, 0, stream>>>(Hs, Ht, Hm, attn_w, offsets, srcs, agg_bf, M);

    // out = agg @ Wo + bo
    dim3 go(128 / 64, (M + 63) / 64);
    gemm_out_kernel<<<go, 256, 0, stream>>>(agg_bf, WThi + (size_t)1152 * 128, bo,
                                            (float*)d_out, M, 128);
}

// Round 7
// 357.491 us; speedup vs baseline: 13.7202x; 1.0426x over previous
//
#include <hip/hip_runtime.h>
#include <math.h>

// InterRankAttention — R7: XCD-aware block swizzle on the merged hidden GEMM
// (all 18 column-blocks of a row-tile land on one XCD -> A-tile + weights stay
// in that XCD's 4MB L2; A HBM re-reads collapse toward compulsory).
// Rest unchanged from R6: split-bf16 hi/lo MFMA hidden GEMMs, bf16 H-storage,
// exp2-domain pk attention, parallel CSR scan.

typedef __bf16 bf16x8 __attribute__((ext_vector_type(8)));
typedef float  f32x4  __attribute__((ext_vector_type(4)));
typedef float  f32x2  __attribute__((ext_vector_type(2)));

__device__ __forceinline__ unsigned short f2bf(float x) {
    unsigned u = __float_as_uint(x);
    u += 0x7FFFu + ((u >> 16) & 1u);   // round-to-nearest-even
    return (unsigned short)(u >> 16);
}
__device__ __forceinline__ float bf2f(unsigned short b) {
    return __uint_as_float(((unsigned)b) << 16);
}
__device__ __forceinline__ f32x2 up2(unsigned u) {   // dword = 2 bf16 -> f32x2
    f32x2 r;
    r.x = __uint_as_float(u << 16);
    r.y = __uint_as_float(u & 0xFFFF0000u);
    return r;
}
__device__ __forceinline__ float exp2_fast(float x) {
#if __has_builtin(__builtin_amdgcn_exp2f)
    return __builtin_amdgcn_exp2f(x);
#else
    return exp2f(x);
#endif
}

// gelu in exp2 domain: gelu(x) = x - x/(2^(C1*x + C2*x^3) + 1)
__device__ __forceinline__ f32x2 gelu2(f32x2 v) {
    f32x2 v2 = v * v;
    f32x2 u  = v * (v2 * 0.10294355f + 2.30220820f);
    f32x2 e;
    e.x = exp2_fast(u.x);
    e.y = exp2_fast(u.y);
    f32x2 r;
    r.x = __builtin_amdgcn_rcpf(e.x + 1.0f);
    r.y = __builtin_amdgcn_rcpf(e.y + 1.0f);
    return v - v * r;
}

__device__ __forceinline__ float edge_logit(uint4 h,
    f32x2 ht0, f32x2 ht1, f32x2 ht2, f32x2 ht3,
    f32x2 aw0, f32x2 aw1, f32x2 aw2, f32x2 aw3) {
    f32x2 qv = gelu2(up2(h.x) + ht0) * aw0;
    qv += gelu2(up2(h.y) + ht1) * aw1;
    qv += gelu2(up2(h.z) + ht2) * aw2;
    qv += gelu2(up2(h.w) + ht3) * aw3;
    return qv.x + qv.y;
}

// ---------------- feature cast: f32 -> bf16 hi/lo ----------------
__global__ __launch_bounds__(256)
void cast_split_kernel(const float* __restrict__ src, const float* __restrict__ tgt,
                       unsigned short* __restrict__ shi, unsigned short* __restrict__ slo,
                       unsigned short* __restrict__ thi, unsigned short* __restrict__ tlo,
                       int n4src, int n4tot) {
    int i = blockIdx.x * blockDim.x + threadIdx.x;
    if (i >= n4tot) return;
    const float* in; unsigned short *hi, *lo; int j;
    if (i < n4src) { in = src; hi = shi; lo = slo; j = i; }
    else           { in = tgt; hi = thi; lo = tlo; j = i - n4src; }
    float4 v = *(const float4*)(in + (size_t)j * 4);
    ushort4 h, l;
    h.x = f2bf(v.x); l.x = f2bf(v.x - bf2f(h.x));
    h.y = f2bf(v.y); l.y = f2bf(v.y - bf2f(h.y));
    h.z = f2bf(v.z); l.z = f2bf(v.z - bf2f(h.z));
    h.w = f2bf(v.w); l.w = f2bf(v.w - bf2f(h.w));
    *(ushort4*)(hi + (size_t)j * 4) = h;
    *(ushort4*)(lo + (size_t)j * 4) = l;
}

// ---------------- weight prep: WT_hi/WT_lo [1280][128] bf16 + bias_cat[640] ----------------
__global__ __launch_bounds__(128)
void prep_weights_kernel(const float* __restrict__ Ws, const float* __restrict__ Wm,
                         const float* __restrict__ Wt, const float* __restrict__ Wo,
                         const float* __restrict__ bs, const float* __restrict__ bm,
                         unsigned short* __restrict__ WThi, unsigned short* __restrict__ WTlo,
                         float* __restrict__ bias_cat) {
    int n = blockIdx.x, k = threadIdx.x;
    float w;
    if      (n < 512)  w = Ws[(size_t)k * 512 + n];
    else if (n < 640)  w = Wm[(size_t)k * 128 + (n - 512)];
    else if (n < 1152) w = Wt[(size_t)k * 512 + (n - 640)];
    else               w = Wo[(size_t)k * 128 + (n - 1152)];
    unsigned short hi = f2bf(w);
    WThi[(size_t)n * 128 + k] = hi;
    WTlo[(size_t)n * 128 + k] = f2bf(w - bf2f(hi));
    if (k == 0 && n < 640) bias_cat[n] = (n < 512) ? bs[n] : bm[n - 512];
}

// ---------------- CSR build ----------------
__global__ void hist_kernel(const int* __restrict__ tgt, int* __restrict__ counts, int E) {
    int e = blockIdx.x * blockDim.x + threadIdx.x;
    if (e < E) atomicAdd(&counts[tgt[e]], 1);
}

__global__ __launch_bounds__(256)
void scan_partial_kernel(const int* __restrict__ counts, int* __restrict__ partials, int M) {
    __shared__ int sdata[256];
    int b = blockIdx.x, tid = threadIdx.x;
    int base = b * 1024 + tid * 4;
    int s = 0;
#pragma unroll
    for (int k = 0; k < 4; ++k) { int idx = base + k; if (idx < M) s += counts[idx]; }
    sdata[tid] = s; __syncthreads();
    for (int d = 128; d > 0; d >>= 1) {
        if (tid < d) sdata[tid] += sdata[tid + d];
        __syncthreads();
    }
    if (tid == 0) partials[b] = sdata[0];
}

__global__ __launch_bounds__(64)
void scan_partials_kernel(const int* __restrict__ partials, int* __restrict__ pbase,
                          int* __restrict__ offsets, int P, int M) {
    int lane = threadIdx.x;
    int own = (lane < P) ? partials[lane] : 0;
    int v = own;
    for (int d = 1; d < 64; d <<= 1) {
        int o = __shfl_up(v, d);
        if (lane >= d) v += o;
    }
    if (lane < P) pbase[lane] = v - own;
    if (lane == 63) offsets[M] = v;
}

__global__ __launch_bounds__(256)
void scan_final_kernel(const int* __restrict__ counts, const int* __restrict__ pbase,
                       int* __restrict__ offsets, int M) {
    __shared__ int sdata[256];
    int b = blockIdx.x, tid = threadIdx.x;
    int base = b * 1024 + tid * 4;
    int c0 = 0, c1 = 0, c2 = 0, c3 = 0;
    if (base + 0 < M) c0 = counts[base + 0];
    if (base + 1 < M) c1 = counts[base + 1];
    if (base + 2 < M) c2 = counts[base + 2];
    if (base + 3 < M) c3 = counts[base + 3];
    int s = c0 + c1 + c2 + c3;
    sdata[tid] = s; __syncthreads();
    int v = s;
    for (int d = 1; d < 256; d <<= 1) {
        int o = (tid >= d) ? sdata[tid - d] : 0;
        __syncthreads();
        v += o;
        sdata[tid] = v;
        __syncthreads();
    }
    int ex = pbase[b] + v - s;
    if (base + 0 < M) offsets[base + 0] = ex;
    if (base + 1 < M) offsets[base + 1] = ex + c0;
    if (base + 2 < M) offsets[base + 2] = ex + c0 + c1;
    if (base + 3 < M) offsets[base + 3] = ex + c0 + c1 + c2;
}

__global__ void scatter_kernel(const int* __restrict__ tgt, const int* __restrict__ src,
                               const int* __restrict__ offsets,
                               int* __restrict__ cursor, int* __restrict__ srcs_sorted, int E) {
    int e = blockIdx.x * blockDim.x + threadIdx.x;
    if (e < E) {
        int t = tgt[e];
        int r = atomicAdd(&cursor[t], 1);
        srcs_sorted[offsets[t] + r] = src[e];
    }
}

// ---------------- merged split-precision hidden GEMM, XCD-swizzled ----------------
// 1-D grid. Linear id i: xcd = i&7 processes all 18 col-blocks of row_tile
// (rg*8 + xcd) consecutively -> A tile + weights L2-resident per XCD.
// col-blocks 0..9: [Hs|Hm] = src@[Ws|Wm]+[bs|bm]; 10..17: Ht = tgt@Wt+bt.
__global__ __launch_bounds__(256, 4)
void gemm_hidden_kernel(const unsigned short* __restrict__ shi, const unsigned short* __restrict__ slo,
                        const unsigned short* __restrict__ thi, const unsigned short* __restrict__ tlo,
                        const unsigned short* __restrict__ WThi, const unsigned short* __restrict__ WTlo,
                        const float* __restrict__ bias_cat, const float* __restrict__ bt,
                        unsigned short* __restrict__ Hs, unsigned short* __restrict__ Hm,
                        unsigned short* __restrict__ Ht, int N, int M) {
    __shared__ unsigned short Ahi[64 * 72], Alo[64 * 72];
    __shared__ unsigned short Bhi[64 * 72], Blo[64 * 72];

    int i = blockIdx.x;
    int x = i & 7;            // presumed XCD (round-robin dispatch heuristic)
    int k = i >> 3;
    int cb = k % 18;          // column block: 0..9 side0, 10..17 side1
    int rg = k / 18;          // row group
    int row_tile = rg * 8 + x;

    bool side1 = cb >= 10;
    const unsigned short* Ahi_g = side1 ? thi : shi;
    const unsigned short* Alo_g = side1 ? tlo : slo;
    int rows = side1 ? M : N;
    int row0 = row_tile * 64;
    if (row0 >= rows) return;
    int colL = side1 ? (cb - 10) * 64 : cb * 64;   // logical output col
    int colW = side1 ? 640 + colL : colL;          // row in WT
    const float* bias = side1 ? bt : bias_cat;

    int tid = threadIdx.x;
    int wid = tid >> 6, lane = tid & 63;
    int wm = (wid >> 1) * 32, wn = (wid & 1) * 32;
    int g = lane >> 4, r16 = lane & 15;

    f32x4 acc00 = {0.f, 0.f, 0.f, 0.f}, acc01 = acc00, acc10 = acc00, acc11 = acc00;

    for (int kb = 0; kb < 128; kb += 64) {
#pragma unroll
        for (int l = 0; l < 2; ++l) {
            int idx = l * 256 + tid;
            int r = idx >> 3, c8 = idx & 7;
            int row = row0 + r;
            uint4 vh = make_uint4(0, 0, 0, 0), vl = vh;
            if (row < rows) {
                vh = *(const uint4*)(Ahi_g + (size_t)row * 128 + kb + c8 * 8);
                vl = *(const uint4*)(Alo_g + (size_t)row * 128 + kb + c8 * 8);
            }
            *(uint4*)(&Ahi[r * 72 + c8 * 8]) = vh;
            *(uint4*)(&Alo[r * 72 + c8 * 8]) = vl;
            uint4 wh = *(const uint4*)(WThi + (size_t)(colW + r) * 128 + kb + c8 * 8);
            uint4 wl = *(const uint4*)(WTlo + (size_t)(colW + r) * 128 + kb + c8 * 8);
            *(uint4*)(&Bhi[r * 72 + c8 * 8]) = wh;
            *(uint4*)(&Blo[r * 72 + c8 * 8]) = wl;
        }
        __syncthreads();

#pragma unroll
        for (int kk = 0; kk < 2; ++kk) {
            int k0 = kk * 32 + g * 8;
            bf16x8 ah0 = *(const bf16x8*)(&Ahi[(wm + r16) * 72 + k0]);
            bf16x8 ah1 = *(const bf16x8*)(&Ahi[(wm + 16 + r16) * 72 + k0]);
            bf16x8 al0 = *(const bf16x8*)(&Alo[(wm + r16) * 72 + k0]);
            bf16x8 al1 = *(const bf16x8*)(&Alo[(wm + 16 + r16) * 72 + k0]);
            bf16x8 bh0 = *(const bf16x8*)(&Bhi[(wn + r16) * 72 + k0]);
            bf16x8 bh1 = *(const bf16x8*)(&Bhi[(wn + 16 + r16) * 72 + k0]);
            bf16x8 bl0 = *(const bf16x8*)(&Blo[(wn + r16) * 72 + k0]);
            bf16x8 bl1 = *(const bf16x8*)(&Blo[(wn + 16 + r16) * 72 + k0]);
            acc00 = __builtin_amdgcn_mfma_f32_16x16x32_bf16(ah0, bh0, acc00, 0, 0, 0);
            acc00 = __builtin_amdgcn_mfma_f32_16x16x32_bf16(ah0, bl0, acc00, 0, 0, 0);
            acc00 = __builtin_amdgcn_mfma_f32_16x16x32_bf16(al0, bh0, acc00, 0, 0, 0);
            acc01 = __builtin_amdgcn_mfma_f32_16x16x32_bf16(ah0, bh1, acc01, 0, 0, 0);
            acc01 = __builtin_amdgcn_mfma_f32_16x16x32_bf16(ah0, bl1, acc01, 0, 0, 0);
            acc01 = __builtin_amdgcn_mfma_f32_16x16x32_bf16(al0, bh1, acc01, 0, 0, 0);
            acc10 = __builtin_amdgcn_mfma_f32_16x16x32_bf16(ah1, bh0, acc10, 0, 0, 0);
            acc10 = __builtin_amdgcn_mfma_f32_16x16x32_bf16(ah1, bl0, acc10, 0, 0, 0);
            acc10 = __builtin_amdgcn_mfma_f32_16x16x32_bf16(al1, bh0, acc10, 0, 0, 0);
            acc11 = __builtin_amdgcn_mfma_f32_16x16x32_bf16(ah1, bh1, acc11, 0, 0, 0);
            acc11 = __builtin_amdgcn_mfma_f32_16x16x32_bf16(ah1, bl1, acc11, 0, 0, 0);
            acc11 = __builtin_amdgcn_mfma_f32_16x16x32_bf16(al1, bh1, acc11, 0, 0, 0);
        }
        __syncthreads();
    }

    int c0 = colL + wn + r16;
    int c1 = c0 + 16;
    float bv0 = bias[c0], bv1 = bias[c1];
#pragma unroll
    for (int ii = 0; ii < 4; ++ii) {
        int rA = row0 + wm + g * 4 + ii;
        int rB = rA + 16;
        if (rA < rows) {
            float o0 = acc00[ii] + bv0, o1 = acc01[ii] + bv1;
            if (side1) {
                Ht[(size_t)rA * 512 + c0] = f2bf(o0);
                Ht[(size_t)rA * 512 + c1] = f2bf(o1);
            } else {
                if (c0 < 512) Hs[(size_t)rA * 512 + c0] = f2bf(o0);
                else          Hm[(size_t)rA * 128 + (c0 - 512)] = f2bf(o0);
                if (c1 < 512) Hs[(size_t)rA * 512 + c1] = f2bf(o1);
                else          Hm[(size_t)rA * 128 + (c1 - 512)] = f2bf(o1);
            }
        }
        if (rB < rows) {
            float o0 = acc10[ii] + bv0, o1 = acc11[ii] + bv1;
            if (side1) {
                Ht[(size_t)rB * 512 + c0] = f2bf(o0);
                Ht[(size_t)rB * 512 + c1] = f2bf(o1);
            } else {
                if (c0 < 512) Hs[(size_t)rB * 512 + c0] = f2bf(o0);
                else          Hm[(size_t)rB * 128 + (c0 - 512)] = f2bf(o0);
                if (c1 < 512) Hs[(size_t)rB * 512 + c1] = f2bf(o1);
                else          Hm[(size_t)rB * 128 + (c1 - 512)] = f2bf(o1);
            }
        }
    }
}

// ---------------- output GEMM: out[M x 128] f32 = agg(bf16) @ Wo_hi + bo ----------------
__global__ __launch_bounds__(256, 4)
void gemm_out_kernel(const unsigned short* __restrict__ A,
                     const unsigned short* __restrict__ BT,
                     const float* __restrict__ bias,
                     float* __restrict__ C, int Mrows, int Ntot) {
    __shared__ unsigned short As[64 * 136];
    __shared__ unsigned short Bs[64 * 136];
    int tid = threadIdx.x;
    int row0 = blockIdx.y * 64, col0 = blockIdx.x * 64;

#pragma unroll
    for (int l = 0; l < 4; ++l) {
        int idx = l * 256 + tid;
        int r = idx >> 4, c8 = idx & 15;
        int row = row0 + r;
        uint4 v = make_uint4(0, 0, 0, 0);
        if (row < Mrows) v = *(const uint4*)(A + (size_t)row * 128 + c8 * 8);
        *(uint4*)(&As[r * 136 + c8 * 8]) = v;
    }
#pragma unroll
    for (int l = 0; l < 4; ++l) {
        int idx = l * 256 + tid;
        int r = idx >> 4, c8 = idx & 15;
        uint4 v = *(const uint4*)(BT + (size_t)(col0 + r) * 128 + c8 * 8);
        *(uint4*)(&Bs[r * 136 + c8 * 8]) = v;
    }
    __syncthreads();

    int wid = tid >> 6, lane = tid & 63;
    int wm = (wid >> 1) * 32, wn = (wid & 1) * 32;
    int g = lane >> 4, r16 = lane & 15;

    f32x4 acc00 = {0.f, 0.f, 0.f, 0.f}, acc01 = acc00, acc10 = acc00, acc11 = acc00;

#pragma unroll
    for (int kk = 0; kk < 4; ++kk) {
        int k0 = kk * 32 + g * 8;
        bf16x8 a0 = *(const bf16x8*)(&As[(wm + r16) * 136 + k0]);
        bf16x8 a1 = *(const bf16x8*)(&As[(wm + 16 + r16) * 136 + k0]);
        bf16x8 b0 = *(const bf16x8*)(&Bs[(wn + r16) * 136 + k0]);
        bf16x8 b1 = *(const bf16x8*)(&Bs[(wn + 16 + r16) * 136 + k0]);
        acc00 = __builtin_amdgcn_mfma_f32_16x16x32_bf16(a0, b0, acc00, 0, 0, 0);
        acc01 = __builtin_amdgcn_mfma_f32_16x16x32_bf16(a0, b1, acc01, 0, 0, 0);
        acc10 = __builtin_amdgcn_mfma_f32_16x16x32_bf16(a1, b0, acc10, 0, 0, 0);
        acc11 = __builtin_amdgcn_mfma_f32_16x16x32_bf16(a1, b1, acc11, 0, 0, 0);
    }

    float bv0 = bias[col0 + wn + r16];
    float bv1 = bias[col0 + wn + 16 + r16];
#pragma unroll
    for (int i = 0; i < 4; ++i) {
        int rA = row0 + wm + g * 4 + i;
        int rB = rA + 16;
        if (rA < Mrows) {
            C[(size_t)rA * Ntot + col0 + wn + r16]      = acc00[i] + bv0;
            C[(size_t)rA * Ntot + col0 + wn + 16 + r16] = acc01[i] + bv1;
        }
        if (rB < Mrows) {
            C[(size_t)rB * Ntot + col0 + wn + r16]      = acc10[i] + bv0;
            C[(size_t)rB * Ntot + col0 + wn + 16 + r16] = acc11[i] + bv1;
        }
    }
}

// ---------------- fused per-target online-softmax attention + aggregation ----------------
__global__ __launch_bounds__(256)
void attn_kernel(const unsigned short* __restrict__ Hs, const unsigned short* __restrict__ Ht,
                 const unsigned short* __restrict__ Hm, const float* __restrict__ attn_w,
                 const int* __restrict__ offsets, const int* __restrict__ srcs,
                 unsigned short* __restrict__ agg, int M) {
    int wave = threadIdx.x >> 6;
    int lane = threadIdx.x & 63;
    int t = blockIdx.x * 4 + wave;
    if (t >= M) return;

    int j0 = lane << 3;
    uint4 h = *(const uint4*)(Ht + (size_t)t * 512 + j0);
    f32x2 ht0 = up2(h.x), ht1 = up2(h.y), ht2 = up2(h.z), ht3 = up2(h.w);
    const float L2E = 1.4426950408889634f;
    float4 a0 = *(const float4*)(attn_w + j0);
    float4 a1 = *(const float4*)(attn_w + j0 + 4);
    f32x2 aw0 = {a0.x * L2E, a0.y * L2E};
    f32x2 aw1 = {a0.z * L2E, a0.w * L2E};
    f32x2 aw2 = {a1.x * L2E, a1.y * L2E};
    f32x2 aw3 = {a1.z * L2E, a1.w * L2E};

    int off = offsets[t];
    int end = offsets[t + 1];

    float m = -INFINITY, den = 0.f;
    f32x2 acc = {0.f, 0.f};
    int hm_off = lane << 1;

    int i = off;
    for (; i + 3 < end; i += 4) {
        int s0 = srcs[i], s1 = srcs[i + 1], s2 = srcs[i + 2], s3 = srcs[i + 3];
        uint4 hA = *(const uint4*)(Hs + (size_t)s0 * 512 + j0);
        uint4 hB = *(const uint4*)(Hs + (size_t)s1 * 512 + j0);
        uint4 hC = *(const uint4*)(Hs + (size_t)s2 * 512 + j0);
        uint4 hD = *(const uint4*)(Hs + (size_t)s3 * 512 + j0);
        unsigned mA = *(const unsigned*)(Hm + (size_t)s0 * 128 + hm_off);
        unsigned mB = *(const unsigned*)(Hm + (size_t)s1 * 128 + hm_off);
        unsigned mC = *(const unsigned*)(Hm + (size_t)s2 * 128 + hm_off);
        unsigned mD = *(const unsigned*)(Hm + (size_t)s3 * 128 + hm_off);
        float q0 = edge_logit(hA, ht0, ht1, ht2, ht3, aw0, aw1, aw2, aw3);
        float q1 = edge_logit(hB, ht0, ht1, ht2, ht3, aw0, aw1, aw2, aw3);
        float q2 = edge_logit(hC, ht0, ht1, ht2, ht3, aw0, aw1, aw2, aw3);
        float q3 = edge_logit(hD, ht0, ht1, ht2, ht3, aw0, aw1, aw2, aw3);
        q0 += __shfl_xor(q0, 1); q1 += __shfl_xor(q1, 1); q2 += __shfl_xor(q2, 1); q3 += __shfl_xor(q3, 1);
        q0 += __shfl_xor(q0, 2); q1 += __shfl_xor(q1, 2); q2 += __shfl_xor(q2, 2); q3 += __shfl_xor(q3, 2);
        q0 += __shfl_xor(q0, 4); q1 += __shfl_xor(q1, 4); q2 += __shfl_xor(q2, 4); q3 += __shfl_xor(q3, 4);
        q0 += __shfl_xor(q0, 8); q1 += __shfl_xor(q1, 8); q2 += __shfl_xor(q2, 8); q3 += __shfl_xor(q3, 8);

        float nm = fmaxf(fmaxf(fmaxf(q0, q1), fmaxf(q2, q3)), m);
        float sc = exp2_fast(m - nm);
        float p0 = exp2_fast(q0 - nm);
        float p1 = exp2_fast(q1 - nm);
        float p2 = exp2_fast(q2 - nm);
        float p3 = exp2_fast(q3 - nm);
        den = fmaf(den, sc, (p0 + p1) + (p2 + p3));
        acc = acc * sc;
        acc += p0 * up2(mA);
        acc += p1 * up2(mB);
        acc += p2 * up2(mC);
        acc += p3 * up2(mD);
        m = nm;
    }
    for (; i < end; ++i) {
        int s0 = srcs[i];
        uint4 hA = *(const uint4*)(Hs + (size_t)s0 * 512 + j0);
        unsigned mA = *(const unsigned*)(Hm + (size_t)s0 * 128 + hm_off);
        float q0 = edge_logit(hA, ht0, ht1, ht2, ht3, aw0, aw1, aw2, aw3);
        q0 += __shfl_xor(q0, 1);
        q0 += __shfl_xor(q0, 2);
        q0 += __shfl_xor(q0, 4);
        q0 += __shfl_xor(q0, 8);
        float nm = fmaxf(m, q0);
        float sc = exp2_fast(m - nm);
        float p0 = exp2_fast(q0 - nm);
        den = fmaf(den, sc, p0);
        acc = acc * sc + p0 * up2(mA);
        m = nm;
    }
    float r = (end > off) ? __builtin_amdgcn_rcpf(den) : 0.0f;
    ushort2 o;
    o.x = f2bf(acc.x * r);
    o.y = f2bf(acc.y * r);
    *(ushort2*)(agg + (size_t)t * 128 + hm_off) = o;
}

extern "C" void kernel_launch(void* const* d_in, const int* in_sizes, int n_in,
                              void* d_out, int out_size, void* d_ws, size_t ws_size,
                              hipStream_t stream) {
    const float* src_f  = (const float*)d_in[0];
    const float* tgt_f  = (const float*)d_in[1];
    const int*   e_tgt  = (const int*)d_in[2];
    const int*   e_src  = (const int*)d_in[3];
    const float* Ws     = (const float*)d_in[4];
    const float* bs     = (const float*)d_in[5];
    const float* Wt     = (const float*)d_in[6];
    const float* bt     = (const float*)d_in[7];
    const float* attn_w = (const float*)d_in[8];
    const float* Wm     = (const float*)d_in[9];
    const float* bm     = (const float*)d_in[10];
    const float* Wo     = (const float*)d_in[11];
    const float* bo     = (const float*)d_in[12];

    int N = in_sizes[0] / 128;
    int M = in_sizes[1] / 128;
    int E = in_sizes[2];

    char* ws = (char*)d_ws;
    size_t woff = 0;
    auto alloc = [&](size_t bytes) -> void* {
        void* p = ws + woff;
        woff += ((bytes + 255) / 256) * 256;
        return p;
    };
    unsigned short* Hs       = (unsigned short*)alloc((size_t)N * 512 * 2);
    unsigned short* Ht       = (unsigned short*)alloc((size_t)M * 512 * 2);
    unsigned short* Hm       = (unsigned short*)alloc((size_t)N * 128 * 2);
    unsigned short* agg_bf   = (unsigned short*)alloc((size_t)M * 128 * 2);
    unsigned short* shi      = (unsigned short*)alloc((size_t)N * 128 * 2);
    unsigned short* slo      = (unsigned short*)alloc((size_t)N * 128 * 2);
    unsigned short* thi      = (unsigned short*)alloc((size_t)M * 128 * 2);
    unsigned short* tlo      = (unsigned short*)alloc((size_t)M * 128 * 2);
    unsigned short* WThi     = (unsigned short*)alloc((size_t)1280 * 128 * 2);
    unsigned short* WTlo     = (unsigned short*)alloc((size_t)1280 * 128 * 2);
    float*          bias_cat = (float*)alloc(640 * 4);
    int*            counts   = (int*)alloc((size_t)M * 4);
    int*            cursor   = (int*)alloc((size_t)M * 4);
    int*            offsets  = (int*)alloc((size_t)(M + 1) * 4);
    int*            srcs     = (int*)alloc((size_t)E * 4);
    int*            partials = (int*)alloc(64 * 4);
    int*            pbase    = (int*)alloc(64 * 4);

    hipMemsetAsync(counts, 0, (size_t)M * 4, stream);
    hipMemsetAsync(cursor, 0, (size_t)M * 4, stream);

    const int tb = 256;
    int P = (M + 1023) / 1024;

    // CSR build
    hist_kernel<<<(E + tb - 1) / tb, tb, 0, stream>>>(e_tgt, counts, E);
    scan_partial_kernel<<<P, 256, 0, stream>>>(counts, partials, M);
    scan_partials_kernel<<<1, 64, 0, stream>>>(partials, pbase, offsets, P, M);
    scan_final_kernel<<<P, 256, 0, stream>>>(counts, pbase, offsets, M);
    scatter_kernel<<<(E + tb - 1) / tb, tb, 0, stream>>>(e_tgt, e_src, offsets, cursor, srcs, E);

    // Feature hi/lo split + weight prep
    int n4src = N * 32, n4tot = (N + M) * 32;
    cast_split_kernel<<<(n4tot + tb - 1) / tb, tb, 0, stream>>>(src_f, tgt_f, shi, slo, thi, tlo,
                                                               n4src, n4tot);
    prep_weights_kernel<<<1280, 128, 0, stream>>>(Ws, Wm, Wt, Wo, bs, bm, WThi, WTlo, bias_cat);

    // Merged hidden GEMMs, XCD-swizzled 1-D grid: 8 xcds * 18 cols * row-groups
    int rowsMax = (N > M) ? N : M;
    int nRowTiles = (rowsMax + 63) / 64;
    int nRG = (nRowTiles + 7) / 8;
    gemm_hidden_kernel<<<8 * 18 * nRG, 256, 0, stream>>>(shi, slo, thi, tlo, WThi, WTlo,
                                                         bias_cat, bt, Hs, Hm, Ht, N, M);

    attn_kernel<<<(M + 3) / 4, 256, 0, stream>>>(Hs, Ht, Hm, attn_w, offsets, srcs, agg_bf, M);

    // out = agg @ Wo + bo
    dim3 go(128 / 64, (M + 63) / 64);
    gemm_out_kernel<<<go, 256, 0, stream>>>(agg_bf, WThi + (size_t)1152 * 128, bo,
                                            (float*)d_out, M, 128);
}